// Round 6
// baseline (8850.911 us; speedup 1.0000x reference)
//
#include <hip/hip_runtime.h>

#define N_NODES 100000
#define HID 256
#define F_IN 128
#define BATCH 16384

// ---------------------------------------------------------------- degree count
__global__ __launch_bounds__(256) void count_kernel(const int* __restrict__ dst,
                                                    float* __restrict__ cnt, int E) {
    int i = blockIdx.x * blockDim.x + threadIdx.x;
    if (i < E) unsafeAtomicAdd(&cnt[dst[i]], 1.0f);
}

__global__ __launch_bounds__(256) void invc_kernel(float* __restrict__ cnt, int N) {
    int i = blockIdx.x * blockDim.x + threadIdx.x;
    if (i < N) cnt[i] = 1.0f / fmaxf(cnt[i], 1.0f);
}

// ---------------------------------------------------------------- aggregation
// one float4 per thread; F/4 threads per edge; agg[dst] += X[src]
template <int F>
__global__ __launch_bounds__(256) void agg_kernel(const float* __restrict__ X,
                                                  const int* __restrict__ src,
                                                  const int* __restrict__ dst,
                                                  float* __restrict__ agg, int E) {
    const unsigned C4 = F / 4;
    unsigned t = blockIdx.x * blockDim.x + threadIdx.x;
    unsigned total = (unsigned)E * C4;
    if (t >= total) return;
    unsigned e = t / C4;
    unsigned c = t % C4;
    int s = src[e], d = dst[e];
    const float4 v = *(const float4*)(X + (size_t)s * F + c * 4);
    float* p = agg + (size_t)d * F + c * 4;
    unsafeAtomicAdd(p + 0, v.x);
    unsafeAtomicAdd(p + 1, v.y);
    unsafeAtomicAdd(p + 2, v.z);
    unsafeAtomicAdd(p + 3, v.w);
}

// ---------------------------------------------------------------- fused concat-GEMM
// C[M,256] = relu( (A0*invc[row])[M,K0] @ W0[K0,256] + A1[M,K1] @ W1[K1,256] + bias )
// BM=64, BN=256 (full width -> one block owns a row stripe => C may alias A1 in place)
// 256 threads, each computes 4 rows x 16 cols.
__global__ __launch_bounds__(256) void gemm256(const float* __restrict__ A0,
                                               const float* __restrict__ W0, int K0,
                                               const float* __restrict__ A1,
                                               const float* __restrict__ W1, int K1,
                                               const float* __restrict__ invc,
                                               const float* __restrict__ bias,
                                               float* __restrict__ C, int M) {
    __shared__ float As[16][68];    // transposed A tile: As[k][row]
    __shared__ float Bs[16][260];   // B tile: Bs[k][col], padded stride

    const int tid = threadIdx.x;
    const int tx = tid & 15;          // col quad base: tx*4 + j*64
    const int ty = tid >> 4;          // row quad base: ty*4
    const int m0 = blockIdx.x * 64;

    // A-load mapping: 64 rows x 16 k, float4 along k
    const int lrow = tid >> 2;        // 0..63
    const int lk = (tid & 3) * 4;     // 0,4,8,12

    float acc[4][16] = {};

    for (int part = 0; part < 2; ++part) {
        const float* A = part ? A1 : A0;
        const float* W = part ? W1 : W0;
        const int K = part ? K1 : K0;
        for (int k0 = 0; k0 < K; k0 += 16) {
            // ---- stage A tile (transposed, mean-scale folded for part 0) ----
            float4 av = make_float4(0.f, 0.f, 0.f, 0.f);
            int ar = m0 + lrow;
            if (ar < M) {
                av = *(const float4*)(A + (size_t)ar * K + k0 + lk);
                if (part == 0) {
                    float sc = invc[ar];
                    av.x *= sc; av.y *= sc; av.z *= sc; av.w *= sc;
                }
            }
            As[lk + 0][lrow] = av.x;
            As[lk + 1][lrow] = av.y;
            As[lk + 2][lrow] = av.z;
            As[lk + 3][lrow] = av.w;

            // ---- stage B tile: 16 k-rows x 256 cols = 1024 float4 slots ----
#pragma unroll
            for (int it = 0; it < 4; ++it) {
                int idx = tid + it * 256;
                int row = idx >> 6;
                int col = (idx & 63) * 4;
                *(float4*)&Bs[row][col] = *(const float4*)(W + (size_t)(k0 + row) * 256 + col);
            }

            __syncthreads();
#pragma unroll
            for (int kk = 0; kk < 16; ++kk) {
                float4 a4 = *(const float4*)&As[kk][ty * 4];
                float a_[4] = {a4.x, a4.y, a4.z, a4.w};
#pragma unroll
                for (int j = 0; j < 4; ++j) {
                    float4 b4 = *(const float4*)&Bs[kk][tx * 4 + j * 64];
#pragma unroll
                    for (int i = 0; i < 4; ++i) {
                        acc[i][j * 4 + 0] = fmaf(a_[i], b4.x, acc[i][j * 4 + 0]);
                        acc[i][j * 4 + 1] = fmaf(a_[i], b4.y, acc[i][j * 4 + 1]);
                        acc[i][j * 4 + 2] = fmaf(a_[i], b4.z, acc[i][j * 4 + 2]);
                        acc[i][j * 4 + 3] = fmaf(a_[i], b4.w, acc[i][j * 4 + 3]);
                    }
                }
            }
            __syncthreads();
        }
    }

    // epilogue: bias + relu, float4 stores (writes C rows this block alone read)
#pragma unroll
    for (int j = 0; j < 4; ++j) {
        float4 bb = *(const float4*)(bias + tx * 4 + j * 64);
#pragma unroll
        for (int i = 0; i < 4; ++i) {
            int r = m0 + ty * 4 + i;
            if (r < M) {
                float4 o;
                o.x = fmaxf(acc[i][j * 4 + 0] + bb.x, 0.f);
                o.y = fmaxf(acc[i][j * 4 + 1] + bb.y, 0.f);
                o.z = fmaxf(acc[i][j * 4 + 2] + bb.z, 0.f);
                o.w = fmaxf(acc[i][j * 4 + 3] + bb.w, 0.f);
                *(float4*)(C + (size_t)r * 256 + tx * 4 + j * 64) = o;
            }
        }
    }
}

// ---------------------------------------------------------------- fused MLP head
__global__ __launch_bounds__(256) void head_kernel(const float* __restrict__ h2,
                                                   const int* __restrict__ idxb,
                                                   const float* __restrict__ xtab,
                                                   const float* __restrict__ Wh1,
                                                   const float* __restrict__ bh1,
                                                   const float* __restrict__ Wh2,
                                                   const float* __restrict__ bh2,
                                                   const float* __restrict__ Wh3,
                                                   const float* __restrict__ bh3,
                                                   float* __restrict__ out) {
    __shared__ float zs[4][288];
    const int tid = threadIdx.x;
    const int w = tid >> 6;
    const int lane = tid & 63;
    const int gw = blockIdx.x * 4 + w;
    const int nw = gridDim.x * 4;

    for (int r = gw; r < BATCH; r += nw) {   // uniform trip count across waves
        int node = idxb[r];
        float4 v = *(const float4*)(h2 + (size_t)node * 256 + lane * 4);
        zs[w][lane * 4 + 0] = v.x;
        zs[w][lane * 4 + 1] = v.y;
        zs[w][lane * 4 + 2] = v.z;
        zs[w][lane * 4 + 3] = v.w;
        if (lane < 4) {
            float4 t = *(const float4*)(xtab + (size_t)r * 16 + lane * 4);
            zs[w][256 + lane * 4 + 0] = t.x;
            zs[w][256 + lane * 4 + 1] = t.y;
            zs[w][256 + lane * 4 + 2] = t.z;
            zs[w][256 + lane * 4 + 3] = t.w;
        }
        __syncthreads();

        float acc = bh1[lane];
#pragma unroll 8
        for (int k = 0; k < 272; ++k)
            acc = fmaf(zs[w][k], Wh1[k * 64 + lane], acc);
        float z1 = fmaxf(acc, 0.f);
        __syncthreads();

        float acc2 = (lane < 32) ? bh2[lane] : 0.f;
#pragma unroll
        for (int k = 0; k < 64; ++k) {
            float zk = __shfl(z1, k, 64);
            acc2 = fmaf(zk, Wh2[k * 32 + (lane & 31)], acc2);
        }
        float val = (lane < 32) ? fmaxf(acc2, 0.f) * Wh3[lane] : 0.f;
#pragma unroll
        for (int off = 32; off > 0; off >>= 1) val += __shfl_xor(val, off, 64);
        if (lane == 0) out[r] = val + bh3[0];
    }
}

// ---------------------------------------------------------------- launch
// Workspace layout (floats): cnt[N] | A[N*256] | B[N*256]   -- peak 205.2 MB
//   A: agg1 (stride 128) for layer 1, then re-zeroed as agg2 (stride 256)
//   B: h1, then h2 written IN PLACE by the BN=256 gemm (row-stripe ownership)
extern "C" void kernel_launch(void* const* d_in, const int* in_sizes, int n_in,
                              void* d_out, int out_size, void* d_ws, size_t ws_size,
                              hipStream_t stream) {
    const float* x    = (const float*)d_in[0];
    const int*   edge = (const int*)d_in[1];
    const int*   idxb = (const int*)d_in[2];
    const float* xtab = (const float*)d_in[3];
    const float* Wl1  = (const float*)d_in[4];
    const float* bl1  = (const float*)d_in[5];
    const float* Wr1  = (const float*)d_in[6];
    const float* Wl2  = (const float*)d_in[7];
    const float* bl2  = (const float*)d_in[8];
    const float* Wr2  = (const float*)d_in[9];
    const float* W1   = (const float*)d_in[10];
    const float* b1   = (const float*)d_in[11];
    const float* W2   = (const float*)d_in[12];
    const float* b2   = (const float*)d_in[13];
    const float* W3   = (const float*)d_in[14];
    const float* b3   = (const float*)d_in[15];

    const int E = in_sizes[1] / 2;
    const int* src = edge;
    const int* dst = edge + E;

    float* cnt = (float*)d_ws;                       // N
    float* A   = cnt + N_NODES;                      // N*256
    float* B   = A + (size_t)N_NODES * HID;          // N*256
    float* out = (float*)d_out;

    const int gemm_grid = (N_NODES + 63) / 64;

    // zero cnt + agg1 region (contiguous: N*(1+128) floats)
    hipMemsetAsync(cnt, 0, (size_t)N_NODES * (1 + F_IN) * sizeof(float), stream);

    count_kernel<<<(E + 255) / 256, 256, 0, stream>>>(dst, cnt, E);
    invc_kernel<<<(N_NODES + 255) / 256, 256, 0, stream>>>(cnt, N_NODES);

    // ---- layer 1: agg1 = scatter(x) in A (stride 128); h1 -> B ----
    {
        unsigned total = (unsigned)E * (F_IN / 4);
        agg_kernel<F_IN><<<(total + 255) / 256, 256, 0, stream>>>(x, src, dst, A, E);
        gemm256<<<gemm_grid, 256, 0, stream>>>(A, Wl1, F_IN, x, Wr1, F_IN, cnt, bl1, B, N_NODES);
    }

    // ---- layer 2: agg2 = scatter(h1) in A (stride 256); h2 -> B in place ----
    {
        hipMemsetAsync(A, 0, (size_t)N_NODES * HID * sizeof(float), stream);
        unsigned total = (unsigned)E * (HID / 4);
        agg_kernel<HID><<<(total + 255) / 256, 256, 0, stream>>>(B, src, dst, A, E);
        gemm256<<<gemm_grid, 256, 0, stream>>>(A, Wl2, HID, B, Wr2, HID, cnt, bl2, B, N_NODES);
    }

    // ---- MLP head ----
    head_kernel<<<256, 256, 0, stream>>>(B, idxb, xtab, W1, b1, W2, b2, W3, b3, out);
}

// Round 9
// 1435.873 us; speedup vs baseline: 6.1641x; 6.1641x over previous
//
#include <hip/hip_runtime.h>

#define N_NODES 100000
#define HID 256
#define F_IN 128
#define BATCH 16384

// ---------------------------------------------------------------- CSR build
// degree count (int atomics into rowptr)
__global__ __launch_bounds__(256) void count_kernel(const int* __restrict__ dst,
                                                    int* __restrict__ rowptr, int E) {
    int i = blockIdx.x * blockDim.x + threadIdx.x;
    if (i < E) atomicAdd(&rowptr[dst[i]], 1);
}

// single-block exclusive scan in place over rowptr[N]
__global__ __launch_bounds__(1024) void scan_kernel(int* __restrict__ deg, int N) {
    __shared__ int partial[1024];
    const int tid = threadIdx.x;
    const int chunk = (N + 1023) / 1024;
    const int start = tid * chunk;
    const int end = min(start + chunk, N);
    int sum = 0;
    for (int i = start; i < end; ++i) sum += deg[i];
    partial[tid] = sum;
    __syncthreads();
    for (int off = 1; off < 1024; off <<= 1) {
        int v = (tid >= off) ? partial[tid - off] : 0;
        __syncthreads();
        if (tid >= off) partial[tid] += v;
        __syncthreads();
    }
    int base = (tid == 0) ? 0 : partial[tid - 1];   // exclusive base for this chunk
    for (int i = start; i < end; ++i) {
        int d = deg[i];
        deg[i] = base;
        base += d;
    }
}

// fill: csr[pos] = src. Afterwards rowptr[d] = end(d); start(d) = d ? rowptr[d-1] : 0
__global__ __launch_bounds__(256) void fill_kernel(const int* __restrict__ src,
                                                   const int* __restrict__ dst,
                                                   int* __restrict__ rowptr,
                                                   int* __restrict__ csr, int E) {
    int i = blockIdx.x * blockDim.x + threadIdx.x;
    if (i < E) {
        int pos = atomicAdd(&rowptr[dst[i]], 1);
        csr[pos] = src[i];
    }
}

// ---------------------------------------------------------------- gather-mean
// one wave per node; lane owns a float4 column slice (F=256)
__global__ __launch_bounds__(256) void gather_mean256(const float* __restrict__ X,
                                                      const int* __restrict__ csr,
                                                      const int* __restrict__ rowptr,
                                                      float* __restrict__ out, int N) {
    const int gt = blockIdx.x * blockDim.x + threadIdx.x;
    const int w = gt >> 6;
    const int lane = gt & 63;
    if (w >= N) return;
    const int start = (w == 0) ? 0 : rowptr[w - 1];
    const int end = rowptr[w];
    float4 a0 = make_float4(0.f, 0.f, 0.f, 0.f);
    float4 a1 = make_float4(0.f, 0.f, 0.f, 0.f);
    int j = start;
    for (; j + 2 <= end; j += 2) {
        int s0 = csr[j], s1 = csr[j + 1];
        float4 v0 = *(const float4*)(X + (size_t)s0 * 256 + lane * 4);
        float4 v1 = *(const float4*)(X + (size_t)s1 * 256 + lane * 4);
        a0.x += v0.x; a0.y += v0.y; a0.z += v0.z; a0.w += v0.w;
        a1.x += v1.x; a1.y += v1.y; a1.z += v1.z; a1.w += v1.w;
    }
    if (j < end) {
        int s0 = csr[j];
        float4 v0 = *(const float4*)(X + (size_t)s0 * 256 + lane * 4);
        a0.x += v0.x; a0.y += v0.y; a0.z += v0.z; a0.w += v0.w;
    }
    float inv = 1.0f / fmaxf((float)(end - start), 1.0f);
    float4 o;
    o.x = (a0.x + a1.x) * inv;
    o.y = (a0.y + a1.y) * inv;
    o.z = (a0.z + a1.z) * inv;
    o.w = (a0.w + a1.w) * inv;
    *(float4*)(out + (size_t)w * 256 + lane * 4) = o;
}

// F=128: lane owns a float2 column slice
__global__ __launch_bounds__(256) void gather_mean128(const float* __restrict__ X,
                                                      const int* __restrict__ csr,
                                                      const int* __restrict__ rowptr,
                                                      float* __restrict__ out, int N) {
    const int gt = blockIdx.x * blockDim.x + threadIdx.x;
    const int w = gt >> 6;
    const int lane = gt & 63;
    if (w >= N) return;
    const int start = (w == 0) ? 0 : rowptr[w - 1];
    const int end = rowptr[w];
    float2 a0 = make_float2(0.f, 0.f);
    float2 a1 = make_float2(0.f, 0.f);
    int j = start;
    for (; j + 2 <= end; j += 2) {
        int s0 = csr[j], s1 = csr[j + 1];
        float2 v0 = *(const float2*)(X + (size_t)s0 * 128 + lane * 2);
        float2 v1 = *(const float2*)(X + (size_t)s1 * 128 + lane * 2);
        a0.x += v0.x; a0.y += v0.y;
        a1.x += v1.x; a1.y += v1.y;
    }
    if (j < end) {
        int s0 = csr[j];
        float2 v0 = *(const float2*)(X + (size_t)s0 * 128 + lane * 2);
        a0.x += v0.x; a0.y += v0.y;
    }
    float inv = 1.0f / fmaxf((float)(end - start), 1.0f);
    float2 o;
    o.x = (a0.x + a1.x) * inv;
    o.y = (a0.y + a1.y) * inv;
    *(float2*)(out + (size_t)w * 128 + lane * 2) = o;
}

// ---------------------------------------------------------------- fused concat-GEMM
// C[M,256] = relu( A0[M,K0] @ W0[K0,256] + A1[M,K1] @ W1[K1,256] + bias )
// BM=64, BN=256 (full width -> one block owns a row stripe => C may alias A1 in place)
__global__ __launch_bounds__(256) void gemm256(const float* __restrict__ A0,
                                               const float* __restrict__ W0, int K0,
                                               const float* __restrict__ A1,
                                               const float* __restrict__ W1, int K1,
                                               const float* __restrict__ bias,
                                               float* __restrict__ C, int M) {
    __shared__ float As[16][68];    // transposed A tile: As[k][row]
    __shared__ float Bs[16][260];   // B tile: Bs[k][col]

    const int tid = threadIdx.x;
    const int tx = tid & 15;
    const int ty = tid >> 4;
    const int m0 = blockIdx.x * 64;

    const int lrow = tid >> 2;        // 0..63
    const int lk = (tid & 3) * 4;     // 0,4,8,12

    float acc[4][16] = {};

    for (int part = 0; part < 2; ++part) {
        const float* A = part ? A1 : A0;
        const float* W = part ? W1 : W0;
        const int K = part ? K1 : K0;
        for (int k0 = 0; k0 < K; k0 += 16) {
            float4 av = make_float4(0.f, 0.f, 0.f, 0.f);
            int ar = m0 + lrow;
            if (ar < M) av = *(const float4*)(A + (size_t)ar * K + k0 + lk);
            As[lk + 0][lrow] = av.x;
            As[lk + 1][lrow] = av.y;
            As[lk + 2][lrow] = av.z;
            As[lk + 3][lrow] = av.w;

#pragma unroll
            for (int it = 0; it < 4; ++it) {
                int idx = tid + it * 256;
                int row = idx >> 6;
                int col = (idx & 63) * 4;
                *(float4*)&Bs[row][col] = *(const float4*)(W + (size_t)(k0 + row) * 256 + col);
            }

            __syncthreads();
#pragma unroll
            for (int kk = 0; kk < 16; ++kk) {
                float4 a4 = *(const float4*)&As[kk][ty * 4];
                float a_[4] = {a4.x, a4.y, a4.z, a4.w};
#pragma unroll
                for (int j = 0; j < 4; ++j) {
                    float4 b4 = *(const float4*)&Bs[kk][tx * 4 + j * 64];
#pragma unroll
                    for (int i = 0; i < 4; ++i) {
                        acc[i][j * 4 + 0] = fmaf(a_[i], b4.x, acc[i][j * 4 + 0]);
                        acc[i][j * 4 + 1] = fmaf(a_[i], b4.y, acc[i][j * 4 + 1]);
                        acc[i][j * 4 + 2] = fmaf(a_[i], b4.z, acc[i][j * 4 + 2]);
                        acc[i][j * 4 + 3] = fmaf(a_[i], b4.w, acc[i][j * 4 + 3]);
                    }
                }
            }
            __syncthreads();
        }
    }

#pragma unroll
    for (int j = 0; j < 4; ++j) {
        float4 bb = *(const float4*)(bias + tx * 4 + j * 64);
#pragma unroll
        for (int i = 0; i < 4; ++i) {
            int r = m0 + ty * 4 + i;
            if (r < M) {
                float4 o;
                o.x = fmaxf(acc[i][j * 4 + 0] + bb.x, 0.f);
                o.y = fmaxf(acc[i][j * 4 + 1] + bb.y, 0.f);
                o.z = fmaxf(acc[i][j * 4 + 2] + bb.z, 0.f);
                o.w = fmaxf(acc[i][j * 4 + 3] + bb.w, 0.f);
                *(float4*)(C + (size_t)r * 256 + tx * 4 + j * 64) = o;
            }
        }
    }
}

// ---------------------------------------------------------------- fused MLP head
__global__ __launch_bounds__(256) void head_kernel(const float* __restrict__ h2,
                                                   const int* __restrict__ idxb,
                                                   const float* __restrict__ xtab,
                                                   const float* __restrict__ Wh1,
                                                   const float* __restrict__ bh1,
                                                   const float* __restrict__ Wh2,
                                                   const float* __restrict__ bh2,
                                                   const float* __restrict__ Wh3,
                                                   const float* __restrict__ bh3,
                                                   float* __restrict__ out) {
    __shared__ float zs[4][288];
    const int tid = threadIdx.x;
    const int w = tid >> 6;
    const int lane = tid & 63;
    const int gw = blockIdx.x * 4 + w;
    const int nw = gridDim.x * 4;

    for (int r = gw; r < BATCH; r += nw) {
        int node = idxb[r];
        float4 v = *(const float4*)(h2 + (size_t)node * 256 + lane * 4);
        zs[w][lane * 4 + 0] = v.x;
        zs[w][lane * 4 + 1] = v.y;
        zs[w][lane * 4 + 2] = v.z;
        zs[w][lane * 4 + 3] = v.w;
        if (lane < 4) {
            float4 t = *(const float4*)(xtab + (size_t)r * 16 + lane * 4);
            zs[w][256 + lane * 4 + 0] = t.x;
            zs[w][256 + lane * 4 + 1] = t.y;
            zs[w][256 + lane * 4 + 2] = t.z;
            zs[w][256 + lane * 4 + 3] = t.w;
        }
        __syncthreads();

        float acc = bh1[lane];
#pragma unroll 8
        for (int k = 0; k < 272; ++k)
            acc = fmaf(zs[w][k], Wh1[k * 64 + lane], acc);
        float z1 = fmaxf(acc, 0.f);
        __syncthreads();

        float acc2 = (lane < 32) ? bh2[lane] : 0.f;
#pragma unroll
        for (int k = 0; k < 64; ++k) {
            float zk = __shfl(z1, k, 64);
            acc2 = fmaf(zk, Wh2[k * 32 + (lane & 31)], acc2);
        }
        float val = (lane < 32) ? fmaxf(acc2, 0.f) * Wh3[lane] : 0.f;
#pragma unroll
        for (int off = 32; off > 0; off >>= 1) val += __shfl_xor(val, off, 64);
        if (lane == 0) out[r] = val + bh3[0];
    }
}

// ---------------------------------------------------------------- launch
// Workspace: rowptr int[N] | csr int[E] | A f32[N*256] | B f32[N*256]  (~211.6 MB)
extern "C" void kernel_launch(void* const* d_in, const int* in_sizes, int n_in,
                              void* d_out, int out_size, void* d_ws, size_t ws_size,
                              hipStream_t stream) {
    const float* x    = (const float*)d_in[0];
    const int*   edge = (const int*)d_in[1];
    const int*   idxb = (const int*)d_in[2];
    const float* xtab = (const float*)d_in[3];
    const float* Wl1  = (const float*)d_in[4];
    const float* bl1  = (const float*)d_in[5];
    const float* Wr1  = (const float*)d_in[6];
    const float* Wl2  = (const float*)d_in[7];
    const float* bl2  = (const float*)d_in[8];
    const float* Wr2  = (const float*)d_in[9];
    const float* W1   = (const float*)d_in[10];
    const float* b1   = (const float*)d_in[11];
    const float* W2   = (const float*)d_in[12];
    const float* b2   = (const float*)d_in[13];
    const float* W3   = (const float*)d_in[14];
    const float* b3   = (const float*)d_in[15];

    const int E = in_sizes[1] / 2;
    const int* src = edge;
    const int* dst = edge + E;

    int* rowptr = (int*)d_ws;                              // N ints
    int* csr    = rowptr + N_NODES;                        // E ints
    size_t idx_ints = (size_t)N_NODES + (((size_t)E + 3) & ~(size_t)3);  // 16B align
    float* A = (float*)d_ws + idx_ints;                    // N*256 f32
    float* B = A + (size_t)N_NODES * HID;                  // N*256 f32
    float* out = (float*)d_out;

    const int gemm_grid = (N_NODES + 63) / 64;
    const int gather_grid = (N_NODES + 3) / 4;             // 4 waves/block, 1 node/wave

    // ---- CSR build (once, reused by both layers) ----
    hipMemsetAsync(rowptr, 0, N_NODES * sizeof(int), stream);
    count_kernel<<<(E + 255) / 256, 256, 0, stream>>>(dst, rowptr, E);
    scan_kernel<<<1, 1024, 0, stream>>>(rowptr, N_NODES);
    fill_kernel<<<(E + 255) / 256, 256, 0, stream>>>(src, dst, rowptr, csr, E);

    // ---- layer 1: A = gather-mean(x) [N,128]; B = h1 ----
    gather_mean128<<<gather_grid, 256, 0, stream>>>(x, csr, rowptr, A, N_NODES);
    gemm256<<<gemm_grid, 256, 0, stream>>>(A, Wl1, F_IN, x, Wr1, F_IN, bl1, B, N_NODES);

    // ---- layer 2: A = gather-mean(h1) [N,256]; h2 -> B in place ----
    gather_mean256<<<gather_grid, 256, 0, stream>>>(B, csr, rowptr, A, N_NODES);
    gemm256<<<gemm_grid, 256, 0, stream>>>(A, Wl2, HID, B, Wr2, HID, bl2, B, N_NODES);

    // ---- MLP head ----
    head_kernel<<<256, 256, 0, stream>>>(B, idxb, xtab, W1, b1, W2, b2, W3, b3, out);
}

// Round 10
// 978.066 us; speedup vs baseline: 9.0494x; 1.4681x over previous
//
#include <hip/hip_runtime.h>
#include <hip/hip_bf16.h>

#define N_NODES 100000
#define HID 256
#define F_IN 128
#define BATCH 16384

using short8 = __attribute__((ext_vector_type(8))) short;
using f32x4  = __attribute__((ext_vector_type(4))) float;

__device__ __forceinline__ ushort f2b(float f) {   // f32 -> bf16 bits, RNE
    union { float f; unsigned u; } v{f};
    unsigned r = (v.u + 0x7fffu + ((v.u >> 16) & 1u)) >> 16;
    return (ushort)r;
}
__device__ __forceinline__ float b2f_lo(unsigned u) { return __uint_as_float(u << 16); }
__device__ __forceinline__ float b2f_hi(unsigned u) { return __uint_as_float(u & 0xffff0000u); }

// ---------------------------------------------------------------- CSR build
__global__ __launch_bounds__(256) void count_kernel(const int* __restrict__ dst,
                                                    int* __restrict__ rowptr, int E) {
    int i = blockIdx.x * blockDim.x + threadIdx.x;
    if (i < E) atomicAdd(&rowptr[dst[i]], 1);
}

__global__ __launch_bounds__(1024) void scan_kernel(int* __restrict__ deg, int N) {
    __shared__ int partial[1024];
    const int tid = threadIdx.x;
    const int chunk = (N + 1023) / 1024;
    const int start = tid * chunk;
    const int end = min(start + chunk, N);
    int sum = 0;
    for (int i = start; i < end; ++i) sum += deg[i];
    partial[tid] = sum;
    __syncthreads();
    for (int off = 1; off < 1024; off <<= 1) {
        int v = (tid >= off) ? partial[tid - off] : 0;
        __syncthreads();
        if (tid >= off) partial[tid] += v;
        __syncthreads();
    }
    int base = (tid == 0) ? 0 : partial[tid - 1];
    for (int i = start; i < end; ++i) {
        int d = deg[i];
        deg[i] = base;
        base += d;
    }
}

__global__ __launch_bounds__(256) void fill_kernel(const int* __restrict__ src,
                                                   const int* __restrict__ dst,
                                                   int* __restrict__ rowptr,
                                                   int* __restrict__ csr, int E) {
    int i = blockIdx.x * blockDim.x + threadIdx.x;
    if (i < E) {
        int pos = atomicAdd(&rowptr[dst[i]], 1);
        csr[pos] = src[i];
    }
}

// ---------------------------------------------------------------- conversions
// f32 -> bf16, 4 elements/thread
__global__ __launch_bounds__(256) void cvt_bf16_kernel(const float* __restrict__ in,
                                                       ushort* __restrict__ out, int n4) {
    int i = blockIdx.x * blockDim.x + threadIdx.x;
    if (i < n4) {
        float4 v = ((const float4*)in)[i];
        ushort4 o;
        o.x = f2b(v.x); o.y = f2b(v.y); o.z = f2b(v.z); o.w = f2b(v.w);
        ((ushort4*)out)[i] = o;
    }
}

// W [K][256] f32  ->  Wt [256][K] bf16 (transpose + convert)
__global__ __launch_bounds__(256) void wt_cvt_kernel(const float* __restrict__ W,
                                                     ushort* __restrict__ Wt, int K) {
    int i = blockIdx.x * blockDim.x + threadIdx.x;
    if (i < 256 * K) {
        int c = i / K, k = i - c * K;
        Wt[i] = f2b(W[k * 256 + c]);
    }
}

// ---------------------------------------------------------------- gather-mean (bf16 in/out)
// one wave per node; F=128: lane owns 2 bf16 (uint)
__global__ __launch_bounds__(256) void gather_mean128_b(const ushort* __restrict__ X,
                                                        const int* __restrict__ csr,
                                                        const int* __restrict__ rowptr,
                                                        ushort* __restrict__ out, int N) {
    const int gt = blockIdx.x * blockDim.x + threadIdx.x;
    const int w = gt >> 6;
    const int lane = gt & 63;
    if (w >= N) return;
    const int start = (w == 0) ? 0 : rowptr[w - 1];
    const int end = rowptr[w];
    float a0 = 0.f, a1 = 0.f, b0 = 0.f, b1 = 0.f;
    int j = start;
    for (; j + 2 <= end; j += 2) {
        int s0 = csr[j], s1 = csr[j + 1];
        unsigned v0 = *(const unsigned*)(X + (size_t)s0 * 128 + lane * 2);
        unsigned v1 = *(const unsigned*)(X + (size_t)s1 * 128 + lane * 2);
        a0 += b2f_lo(v0); a1 += b2f_hi(v0);
        b0 += b2f_lo(v1); b1 += b2f_hi(v1);
    }
    if (j < end) {
        unsigned v0 = *(const unsigned*)(X + (size_t)csr[j] * 128 + lane * 2);
        a0 += b2f_lo(v0); a1 += b2f_hi(v0);
    }
    float inv = 1.0f / fmaxf((float)(end - start), 1.0f);
    unsigned o = (unsigned)f2b((a0 + b0) * inv) | ((unsigned)f2b((a1 + b1) * inv) << 16);
    *(unsigned*)(out + (size_t)w * 128 + lane * 2) = o;
}

// F=256: lane owns 4 bf16 (uint2)
__global__ __launch_bounds__(256) void gather_mean256_b(const ushort* __restrict__ X,
                                                        const int* __restrict__ csr,
                                                        const int* __restrict__ rowptr,
                                                        ushort* __restrict__ out, int N) {
    const int gt = blockIdx.x * blockDim.x + threadIdx.x;
    const int w = gt >> 6;
    const int lane = gt & 63;
    if (w >= N) return;
    const int start = (w == 0) ? 0 : rowptr[w - 1];
    const int end = rowptr[w];
    float a0 = 0.f, a1 = 0.f, a2 = 0.f, a3 = 0.f;
    float b0 = 0.f, b1 = 0.f, b2 = 0.f, b3 = 0.f;
    int j = start;
    for (; j + 2 <= end; j += 2) {
        int s0 = csr[j], s1 = csr[j + 1];
        uint2 v0 = *(const uint2*)(X + (size_t)s0 * 256 + lane * 4);
        uint2 v1 = *(const uint2*)(X + (size_t)s1 * 256 + lane * 4);
        a0 += b2f_lo(v0.x); a1 += b2f_hi(v0.x);
        a2 += b2f_lo(v0.y); a3 += b2f_hi(v0.y);
        b0 += b2f_lo(v1.x); b1 += b2f_hi(v1.x);
        b2 += b2f_lo(v1.y); b3 += b2f_hi(v1.y);
    }
    if (j < end) {
        uint2 v0 = *(const uint2*)(X + (size_t)csr[j] * 256 + lane * 4);
        a0 += b2f_lo(v0.x); a1 += b2f_hi(v0.x);
        a2 += b2f_lo(v0.y); a3 += b2f_hi(v0.y);
    }
    float inv = 1.0f / fmaxf((float)(end - start), 1.0f);
    uint2 o;
    o.x = (unsigned)f2b((a0 + b0) * inv) | ((unsigned)f2b((a1 + b1) * inv) << 16);
    o.y = (unsigned)f2b((a2 + b2) * inv) | ((unsigned)f2b((a3 + b3) * inv) << 16);
    *(uint2*)(out + (size_t)w * 256 + lane * 4) = o;
}

// ---------------------------------------------------------------- bf16 MFMA concat-GEMM
// C[M,256] = relu( A0[M,K0]@W0 + A1[M,K1]@W1 + bias ), Wt* pre-transposed [256][K] bf16.
// Block: 256 thr = 4 waves; BM=64, BN=256; wave w owns cols [w*64, w*64+64).
// Per wave: 4x4 fragments of mfma_f32_16x16x32_bf16. In-place C==A1 safe (row stripe).
template <int K0, int K1>
__global__ __launch_bounds__(256) void gemm_mfma(const ushort* __restrict__ A0,
                                                 const ushort* __restrict__ Wt0,
                                                 const ushort* __restrict__ A1,
                                                 const ushort* __restrict__ Wt1,
                                                 const float* __restrict__ bias,
                                                 ushort* __restrict__ C, int M) {
    __shared__ short As[64][40];    // [row][k], +8 pad -> 80B stride (16B aligned)
    __shared__ short Bs[256][40];   // [col][k]

    const int tid = threadIdx.x;
    const int wv = tid >> 6;
    const int lane = tid & 63;
    const int m0 = blockIdx.x * 64;
    const int col0 = wv * 64;
    const int arow = tid >> 2;          // 0..63
    const int akc = (tid & 3) * 8;      // 0,8,16,24
    const int l15 = lane & 15;
    const int lk = (lane >> 4) * 8;     // k base within 32

    f32x4 acc[4][4] = {};

    for (int part = 0; part < 2; ++part) {
        const ushort* A = part ? A1 : A0;
        const ushort* Wt = part ? Wt1 : Wt0;
        const int K = part ? K1 : K0;
        for (int k0 = 0; k0 < K; k0 += 32) {
            // stage A tile [64][32]
            uint4 av = make_uint4(0u, 0u, 0u, 0u);
            int r = m0 + arow;
            if (r < M) av = *(const uint4*)(A + (size_t)r * K + k0 + akc);
            *(uint4*)&As[arow][akc] = av;
            // stage B tile: thread tid -> col tid, 32 bf16 contiguous from Wt
            {
                const ushort* srcp = Wt + (size_t)tid * K + k0;
                uint4 q0 = *(const uint4*)(srcp);
                uint4 q1 = *(const uint4*)(srcp + 8);
                uint4 q2 = *(const uint4*)(srcp + 16);
                uint4 q3 = *(const uint4*)(srcp + 24);
                *(uint4*)&Bs[tid][0] = q0;
                *(uint4*)&Bs[tid][8] = q1;
                *(uint4*)&Bs[tid][16] = q2;
                *(uint4*)&Bs[tid][24] = q3;
            }
            __syncthreads();

            short8 af[4], bg[4];
#pragma unroll
            for (int fi = 0; fi < 4; ++fi)
                af[fi] = *(const short8*)&As[fi * 16 + l15][lk];
#pragma unroll
            for (int fj = 0; fj < 4; ++fj)
                bg[fj] = *(const short8*)&Bs[col0 + fj * 16 + l15][lk];
#pragma unroll
            for (int fi = 0; fi < 4; ++fi)
#pragma unroll
                for (int fj = 0; fj < 4; ++fj)
                    acc[fi][fj] = __builtin_amdgcn_mfma_f32_16x16x32_bf16(
                        af[fi], bg[fj], acc[fi][fj], 0, 0, 0);
            __syncthreads();
        }
    }

    // epilogue: bias + relu -> bf16.  C/D layout: col=lane&15, row=(lane>>4)*4+reg
    const int rbase = (lane >> 4) * 4;
#pragma unroll
    for (int fj = 0; fj < 4; ++fj) {
        int c = col0 + fj * 16 + l15;
        float bv = bias[c];
#pragma unroll
        for (int fi = 0; fi < 4; ++fi) {
#pragma unroll
            for (int rr = 0; rr < 4; ++rr) {
                int r = m0 + fi * 16 + rbase + rr;
                if (r < M) {
                    float o = fmaxf(acc[fi][fj][rr] + bv, 0.f);
                    C[(size_t)r * 256 + c] = f2b(o);
                }
            }
        }
    }
}

// ---------------------------------------------------------------- fused MLP head (h2 bf16)
__global__ __launch_bounds__(256) void head_kernel(const ushort* __restrict__ h2,
                                                   const int* __restrict__ idxb,
                                                   const float* __restrict__ xtab,
                                                   const float* __restrict__ Wh1,
                                                   const float* __restrict__ bh1,
                                                   const float* __restrict__ Wh2,
                                                   const float* __restrict__ bh2,
                                                   const float* __restrict__ Wh3,
                                                   const float* __restrict__ bh3,
                                                   float* __restrict__ out) {
    __shared__ float zs[4][288];
    const int tid = threadIdx.x;
    const int w = tid >> 6;
    const int lane = tid & 63;
    const int gw = blockIdx.x * 4 + w;
    const int nw = gridDim.x * 4;

    for (int r = gw; r < BATCH; r += nw) {
        int node = idxb[r];
        uint2 v = *(const uint2*)(h2 + (size_t)node * 256 + lane * 4);
        zs[w][lane * 4 + 0] = b2f_lo(v.x);
        zs[w][lane * 4 + 1] = b2f_hi(v.x);
        zs[w][lane * 4 + 2] = b2f_lo(v.y);
        zs[w][lane * 4 + 3] = b2f_hi(v.y);
        if (lane < 4) {
            float4 t = *(const float4*)(xtab + (size_t)r * 16 + lane * 4);
            zs[w][256 + lane * 4 + 0] = t.x;
            zs[w][256 + lane * 4 + 1] = t.y;
            zs[w][256 + lane * 4 + 2] = t.z;
            zs[w][256 + lane * 4 + 3] = t.w;
        }
        __syncthreads();

        float acc = bh1[lane];
#pragma unroll 8
        for (int k = 0; k < 272; ++k)
            acc = fmaf(zs[w][k], Wh1[k * 64 + lane], acc);
        float z1 = fmaxf(acc, 0.f);
        __syncthreads();

        float acc2 = (lane < 32) ? bh2[lane] : 0.f;
#pragma unroll
        for (int k = 0; k < 64; ++k) {
            float zk = __shfl(z1, k, 64);
            acc2 = fmaf(zk, Wh2[k * 32 + (lane & 31)], acc2);
        }
        float val = (lane < 32) ? fmaxf(acc2, 0.f) * Wh3[lane] : 0.f;
#pragma unroll
        for (int off = 32; off > 0; off >>= 1) val += __shfl_xor(val, off, 64);
        if (lane == 0) out[r] = val + bh3[0];
    }
}

// ---------------------------------------------------------------- launch
// ws: rowptr int[N] | csr int[E] | xb u16[N*128] | aggA u16[N*256] | h u16[N*256]
//     | Wt1l u16[256*128] | Wt1r u16[256*128] | Wt2l u16[256*256] | Wt2r u16[256*256]
// total ~135 MB
extern "C" void kernel_launch(void* const* d_in, const int* in_sizes, int n_in,
                              void* d_out, int out_size, void* d_ws, size_t ws_size,
                              hipStream_t stream) {
    const float* x    = (const float*)d_in[0];
    const int*   edge = (const int*)d_in[1];
    const int*   idxb = (const int*)d_in[2];
    const float* xtab = (const float*)d_in[3];
    const float* Wl1  = (const float*)d_in[4];
    const float* bl1  = (const float*)d_in[5];
    const float* Wr1  = (const float*)d_in[6];
    const float* Wl2  = (const float*)d_in[7];
    const float* bl2  = (const float*)d_in[8];
    const float* Wr2  = (const float*)d_in[9];
    const float* W1   = (const float*)d_in[10];
    const float* b1   = (const float*)d_in[11];
    const float* W2   = (const float*)d_in[12];
    const float* b2   = (const float*)d_in[13];
    const float* W3   = (const float*)d_in[14];
    const float* b3   = (const float*)d_in[15];

    const int E = in_sizes[1] / 2;
    const int* src = edge;
    const int* dst = edge + E;

    int* rowptr = (int*)d_ws;                                   // N ints
    int* csr    = rowptr + N_NODES;                             // E ints
    size_t idx_ints = (size_t)N_NODES + (((size_t)E + 3) & ~(size_t)3);
    ushort* xb   = (ushort*)((int*)d_ws + idx_ints);            // N*128
    ushort* aggA = xb + (size_t)N_NODES * F_IN;                 // N*256
    ushort* h    = aggA + (size_t)N_NODES * HID;                // N*256
    ushort* Wt1l = h + (size_t)N_NODES * HID;                   // 256*128
    ushort* Wt1r = Wt1l + 256 * F_IN;
    ushort* Wt2l = Wt1r + 256 * F_IN;                           // 256*256
    ushort* Wt2r = Wt2l + 256 * HID;
    float* out = (float*)d_out;

    const int gemm_grid = (N_NODES + 63) / 64;
    const int gather_grid = (N_NODES + 3) / 4;

    // ---- CSR build ----
    hipMemsetAsync(rowptr, 0, N_NODES * sizeof(int), stream);
    count_kernel<<<(E + 255) / 256, 256, 0, stream>>>(dst, rowptr, E);
    scan_kernel<<<1, 1024, 0, stream>>>(rowptr, N_NODES);
    fill_kernel<<<(E + 255) / 256, 256, 0, stream>>>(src, dst, rowptr, csr, E);

    // ---- conversions ----
    {
        int n4 = N_NODES * F_IN / 4;
        cvt_bf16_kernel<<<(n4 + 255) / 256, 256, 0, stream>>>(x, xb, n4);
        wt_cvt_kernel<<<(256 * F_IN + 255) / 256, 256, 0, stream>>>(Wl1, Wt1l, F_IN);
        wt_cvt_kernel<<<(256 * F_IN + 255) / 256, 256, 0, stream>>>(Wr1, Wt1r, F_IN);
        wt_cvt_kernel<<<(256 * HID + 255) / 256, 256, 0, stream>>>(Wl2, Wt2l, HID);
        wt_cvt_kernel<<<(256 * HID + 255) / 256, 256, 0, stream>>>(Wr2, Wt2r, HID);
    }

    // ---- layer 1 ----
    gather_mean128_b<<<gather_grid, 256, 0, stream>>>(xb, csr, rowptr, aggA, N_NODES);
    gemm_mfma<F_IN, F_IN><<<gemm_grid, 256, 0, stream>>>(aggA, Wt1l, xb, Wt1r, bl1, h, N_NODES);

    // ---- layer 2 ----
    gather_mean256_b<<<gather_grid, 256, 0, stream>>>(h, csr, rowptr, aggA, N_NODES);
    gemm_mfma<HID, HID><<<gemm_grid, 256, 0, stream>>>(aggA, Wt2l, h, Wt2r, bl2, h, N_NODES);

    // ---- MLP head ----
    head_kernel<<<256, 256, 0, stream>>>(h, idxb, xtab, W1, b1, W2, b2, W3, b3, out);
}

// Round 12
// 818.976 us; speedup vs baseline: 10.8073x; 1.1943x over previous
//
#include <hip/hip_runtime.h>
#include <hip/hip_bf16.h>

#define N_NODES 100000
#define HID 256
#define F_IN 128
#define BATCH 16384

using short8 = __attribute__((ext_vector_type(8))) short;
using f32x4  = __attribute__((ext_vector_type(4))) float;

__device__ __forceinline__ ushort f2b(float f) {   // f32 -> bf16 bits, RNE
    union { float f; unsigned u; } v{f};
    unsigned r = (v.u + 0x7fffu + ((v.u >> 16) & 1u)) >> 16;
    return (ushort)r;
}
__device__ __forceinline__ float b2f_lo(unsigned u) { return __uint_as_float(u << 16); }
__device__ __forceinline__ float b2f_hi(unsigned u) { return __uint_as_float(u & 0xffff0000u); }

// ---------------------------------------------------------------- CSR build
__global__ __launch_bounds__(256) void count_kernel(const int* __restrict__ dst,
                                                    int* __restrict__ rowptr, int E) {
    int i = blockIdx.x * blockDim.x + threadIdx.x;
    if (i < E) atomicAdd(&rowptr[dst[i]], 1);
}

// ---- multi-block exclusive scan over data[N] (3 phases) ----
// phase 1: per-block (1024 elems) exclusive scan in place + block sums
__global__ __launch_bounds__(256) void scan1(int* __restrict__ data,
                                             int* __restrict__ psum, int N) {
    __shared__ int sh[256];
    const int tid = threadIdx.x;
    const int base = blockIdx.x * 1024;
    const int idx0 = base + tid * 4;
    int v0 = 0, v1 = 0, v2 = 0, v3 = 0;
    if (idx0 + 3 < N) {
        int4 q = *(const int4*)(data + idx0);
        v0 = q.x; v1 = q.y; v2 = q.z; v3 = q.w;
    } else {
        if (idx0 + 0 < N) v0 = data[idx0 + 0];
        if (idx0 + 1 < N) v1 = data[idx0 + 1];
        if (idx0 + 2 < N) v2 = data[idx0 + 2];
        if (idx0 + 3 < N) v3 = data[idx0 + 3];
    }
    int tsum = v0 + v1 + v2 + v3;
    sh[tid] = tsum;
    __syncthreads();
    for (int off = 1; off < 256; off <<= 1) {
        int t = (tid >= off) ? sh[tid - off] : 0;
        __syncthreads();
        if (tid >= off) sh[tid] += t;
        __syncthreads();
    }
    if (tid == 255) psum[blockIdx.x] = sh[255];
    int run = sh[tid] - tsum;   // exclusive prefix within block
    if (idx0 + 3 < N) {
        int4 o;
        o.x = run; run += v0;
        o.y = run; run += v1;
        o.z = run; run += v2;
        o.w = run;
        *(int4*)(data + idx0) = o;
    } else {
        if (idx0 + 0 < N) { data[idx0 + 0] = run; run += v0; }
        if (idx0 + 1 < N) { data[idx0 + 1] = run; run += v1; }
        if (idx0 + 2 < N) { data[idx0 + 2] = run; run += v2; }
    }
}

// phase 2: exclusive scan of block sums (nb <= 128), single block
__global__ __launch_bounds__(128) void scan2(int* __restrict__ psum, int nb) {
    __shared__ int sh[128];
    const int tid = threadIdx.x;
    int v = (tid < nb) ? psum[tid] : 0;
    sh[tid] = v;
    __syncthreads();
    for (int off = 1; off < 128; off <<= 1) {
        int t = (tid >= off) ? sh[tid - off] : 0;
        __syncthreads();
        if (tid >= off) sh[tid] += t;
        __syncthreads();
    }
    if (tid < nb) psum[tid] = sh[tid] - v;
}

// phase 3: add block offsets
__global__ __launch_bounds__(256) void scan3(int* __restrict__ data,
                                             const int* __restrict__ psum, int N) {
    int i = blockIdx.x * blockDim.x + threadIdx.x;
    if (i < N) data[i] += psum[i >> 10];
}

__global__ __launch_bounds__(256) void fill_kernel(const int* __restrict__ src,
                                                   const int* __restrict__ dst,
                                                   int* __restrict__ rowptr,
                                                   int* __restrict__ csr, int E) {
    int i = blockIdx.x * blockDim.x + threadIdx.x;
    if (i < E) {
        int pos = atomicAdd(&rowptr[dst[i]], 1);
        csr[pos] = src[i];
    }
}

// ---------------------------------------------------------------- conversions
__global__ __launch_bounds__(256) void cvt_bf16_kernel(const float* __restrict__ in,
                                                       ushort* __restrict__ out, int n4) {
    int i = blockIdx.x * blockDim.x + threadIdx.x;
    if (i < n4) {
        float4 v = ((const float4*)in)[i];
        ushort4 o;
        o.x = f2b(v.x); o.y = f2b(v.y); o.z = f2b(v.z); o.w = f2b(v.w);
        ((ushort4*)out)[i] = o;
    }
}

// W [K][256] f32  ->  Wt [256][K] bf16 (transpose + convert)
__global__ __launch_bounds__(256) void wt_cvt_kernel(const float* __restrict__ W,
                                                     ushort* __restrict__ Wt, int K) {
    int i = blockIdx.x * blockDim.x + threadIdx.x;
    if (i < 256 * K) {
        int c = i / K, k = i - c * K;
        Wt[i] = f2b(W[k * 256 + c]);
    }
}

// ---------------------------------------------------------------- gather-mean (bf16 in/out)
__global__ __launch_bounds__(256) void gather_mean128_b(const ushort* __restrict__ X,
                                                        const int* __restrict__ csr,
                                                        const int* __restrict__ rowptr,
                                                        ushort* __restrict__ out, int N) {
    const int gt = blockIdx.x * blockDim.x + threadIdx.x;
    const int w = gt >> 6;
    const int lane = gt & 63;
    if (w >= N) return;
    const int start = (w == 0) ? 0 : rowptr[w - 1];
    const int end = rowptr[w];
    float a0 = 0.f, a1 = 0.f, b0 = 0.f, b1 = 0.f;
    int j = start;
    for (; j + 2 <= end; j += 2) {
        int s0 = csr[j], s1 = csr[j + 1];
        unsigned v0 = *(const unsigned*)(X + (size_t)s0 * 128 + lane * 2);
        unsigned v1 = *(const unsigned*)(X + (size_t)s1 * 128 + lane * 2);
        a0 += b2f_lo(v0); a1 += b2f_hi(v0);
        b0 += b2f_lo(v1); b1 += b2f_hi(v1);
    }
    if (j < end) {
        unsigned v0 = *(const unsigned*)(X + (size_t)csr[j] * 128 + lane * 2);
        a0 += b2f_lo(v0); a1 += b2f_hi(v0);
    }
    float inv = 1.0f / fmaxf((float)(end - start), 1.0f);
    unsigned o = (unsigned)f2b((a0 + b0) * inv) | ((unsigned)f2b((a1 + b1) * inv) << 16);
    *(unsigned*)(out + (size_t)w * 128 + lane * 2) = o;
}

__global__ __launch_bounds__(256) void gather_mean256_b(const ushort* __restrict__ X,
                                                        const int* __restrict__ csr,
                                                        const int* __restrict__ rowptr,
                                                        ushort* __restrict__ out, int N) {
    const int gt = blockIdx.x * blockDim.x + threadIdx.x;
    const int w = gt >> 6;
    const int lane = gt & 63;
    if (w >= N) return;
    const int start = (w == 0) ? 0 : rowptr[w - 1];
    const int end = rowptr[w];
    float a0 = 0.f, a1 = 0.f, a2 = 0.f, a3 = 0.f;
    float b0 = 0.f, b1 = 0.f, b2 = 0.f, b3 = 0.f;
    int j = start;
    for (; j + 2 <= end; j += 2) {
        int s0 = csr[j], s1 = csr[j + 1];
        uint2 v0 = *(const uint2*)(X + (size_t)s0 * 256 + lane * 4);
        uint2 v1 = *(const uint2*)(X + (size_t)s1 * 256 + lane * 4);
        a0 += b2f_lo(v0.x); a1 += b2f_hi(v0.x);
        a2 += b2f_lo(v0.y); a3 += b2f_hi(v0.y);
        b0 += b2f_lo(v1.x); b1 += b2f_hi(v1.x);
        b2 += b2f_lo(v1.y); b3 += b2f_hi(v1.y);
    }
    if (j < end) {
        uint2 v0 = *(const uint2*)(X + (size_t)csr[j] * 256 + lane * 4);
        a0 += b2f_lo(v0.x); a1 += b2f_hi(v0.x);
        a2 += b2f_lo(v0.y); a3 += b2f_hi(v0.y);
    }
    float inv = 1.0f / fmaxf((float)(end - start), 1.0f);
    uint2 o;
    o.x = (unsigned)f2b((a0 + b0) * inv) | ((unsigned)f2b((a1 + b1) * inv) << 16);
    o.y = (unsigned)f2b((a2 + b2) * inv) | ((unsigned)f2b((a3 + b3) * inv) << 16);
    *(uint2*)(out + (size_t)w * 256 + lane * 4) = o;
}

// ---------------------------------------------------------------- bf16 MFMA concat-GEMM
// C[M,256] = relu( A0[M,K0]@W0 + A1[M,K1]@W1 + bias ), Wt* pre-transposed [256][K] bf16.
// Block: 256 thr = 4 waves; BM=64, BN=256; wave w owns cols [w*64, w*64+64).
template <int K0, int K1>
__global__ __launch_bounds__(256) void gemm_mfma(const ushort* __restrict__ A0,
                                                 const ushort* __restrict__ Wt0,
                                                 const ushort* __restrict__ A1,
                                                 const ushort* __restrict__ Wt1,
                                                 const float* __restrict__ bias,
                                                 ushort* __restrict__ C, int M) {
    __shared__ short As[64][40];    // [row][k], +8 pad
    __shared__ short Bs[256][40];   // [col][k]

    const int tid = threadIdx.x;
    const int wv = tid >> 6;
    const int lane = tid & 63;
    const int m0 = blockIdx.x * 64;
    const int col0 = wv * 64;
    const int arow = tid >> 2;          // 0..63
    const int akc = (tid & 3) * 8;      // 0,8,16,24
    const int l15 = lane & 15;
    const int lk = (lane >> 4) * 8;     // k base within 32

    f32x4 acc[4][4] = {};

    for (int part = 0; part < 2; ++part) {
        const ushort* A = part ? A1 : A0;
        const ushort* Wt = part ? Wt1 : Wt0;
        const int K = part ? K1 : K0;
        for (int k0 = 0; k0 < K; k0 += 32) {
            uint4 av = make_uint4(0u, 0u, 0u, 0u);
            int r = m0 + arow;
            if (r < M) av = *(const uint4*)(A + (size_t)r * K + k0 + akc);
            *(uint4*)&As[arow][akc] = av;
            {
                const ushort* srcp = Wt + (size_t)tid * K + k0;
                uint4 q0 = *(const uint4*)(srcp);
                uint4 q1 = *(const uint4*)(srcp + 8);
                uint4 q2 = *(const uint4*)(srcp + 16);
                uint4 q3 = *(const uint4*)(srcp + 24);
                *(uint4*)&Bs[tid][0] = q0;
                *(uint4*)&Bs[tid][8] = q1;
                *(uint4*)&Bs[tid][16] = q2;
                *(uint4*)&Bs[tid][24] = q3;
            }
            __syncthreads();

            short8 af[4], bg[4];
#pragma unroll
            for (int fi = 0; fi < 4; ++fi)
                af[fi] = *(const short8*)&As[fi * 16 + l15][lk];
#pragma unroll
            for (int fj = 0; fj < 4; ++fj)
                bg[fj] = *(const short8*)&Bs[col0 + fj * 16 + l15][lk];
#pragma unroll
            for (int fi = 0; fi < 4; ++fi)
#pragma unroll
                for (int fj = 0; fj < 4; ++fj)
                    acc[fi][fj] = __builtin_amdgcn_mfma_f32_16x16x32_bf16(
                        af[fi], bg[fj], acc[fi][fj], 0, 0, 0);
            __syncthreads();
        }
    }

    // epilogue: bias + relu -> bf16.  C/D layout: col=lane&15, row=(lane>>4)*4+reg
    const int rbase = (lane >> 4) * 4;
#pragma unroll
    for (int fj = 0; fj < 4; ++fj) {
        int c = col0 + fj * 16 + l15;
        float bv = bias[c];
#pragma unroll
        for (int fi = 0; fi < 4; ++fi) {
#pragma unroll
            for (int rr = 0; rr < 4; ++rr) {
                int r = m0 + fi * 16 + rbase + rr;
                if (r < M) {
                    float o = fmaxf(acc[fi][fj][rr] + bv, 0.f);
                    C[(size_t)r * 256 + c] = f2b(o);
                }
            }
        }
    }
}

// ---------------------------------------------------------------- fused MLP head (h2 bf16)
__global__ __launch_bounds__(256) void head_kernel(const ushort* __restrict__ h2,
                                                   const int* __restrict__ idxb,
                                                   const float* __restrict__ xtab,
                                                   const float* __restrict__ Wh1,
                                                   const float* __restrict__ bh1,
                                                   const float* __restrict__ Wh2,
                                                   const float* __restrict__ bh2,
                                                   const float* __restrict__ Wh3,
                                                   const float* __restrict__ bh3,
                                                   float* __restrict__ out) {
    __shared__ float zs[4][288];
    const int tid = threadIdx.x;
    const int w = tid >> 6;
    const int lane = tid & 63;
    const int gw = blockIdx.x * 4 + w;
    const int nw = gridDim.x * 4;

    for (int r = gw; r < BATCH; r += nw) {
        int node = idxb[r];
        uint2 v = *(const uint2*)(h2 + (size_t)node * 256 + lane * 4);
        zs[w][lane * 4 + 0] = b2f_lo(v.x);
        zs[w][lane * 4 + 1] = b2f_hi(v.x);
        zs[w][lane * 4 + 2] = b2f_lo(v.y);
        zs[w][lane * 4 + 3] = b2f_hi(v.y);
        if (lane < 4) {
            float4 t = *(const float4*)(xtab + (size_t)r * 16 + lane * 4);
            zs[w][256 + lane * 4 + 0] = t.x;
            zs[w][256 + lane * 4 + 1] = t.y;
            zs[w][256 + lane * 4 + 2] = t.z;
            zs[w][256 + lane * 4 + 3] = t.w;
        }
        __syncthreads();

        float acc = bh1[lane];
#pragma unroll 8
        for (int k = 0; k < 272; ++k)
            acc = fmaf(zs[w][k], Wh1[k * 64 + lane], acc);
        float z1 = fmaxf(acc, 0.f);
        __syncthreads();

        float acc2 = (lane < 32) ? bh2[lane] : 0.f;
#pragma unroll
        for (int k = 0; k < 64; ++k) {
            float zk = __shfl(z1, k, 64);
            acc2 = fmaf(zk, Wh2[k * 32 + (lane & 31)], acc2);
        }
        float val = (lane < 32) ? fmaxf(acc2, 0.f) * Wh3[lane] : 0.f;
#pragma unroll
        for (int off = 32; off > 0; off >>= 1) val += __shfl_xor(val, off, 64);
        if (lane == 0) out[r] = val + bh3[0];
    }
}

// ---------------------------------------------------------------- launch
// ws: rowptr int[N] | csr int[E] | psum int[128] | xb u16[N*128] | aggA u16[N*256]
//     | h u16[N*256] | Wt1l | Wt1r | Wt2l | Wt2r    (~135 MB)
extern "C" void kernel_launch(void* const* d_in, const int* in_sizes, int n_in,
                              void* d_out, int out_size, void* d_ws, size_t ws_size,
                              hipStream_t stream) {
    const float* x    = (const float*)d_in[0];
    const int*   edge = (const int*)d_in[1];
    const int*   idxb = (const int*)d_in[2];
    const float* xtab = (const float*)d_in[3];
    const float* Wl1  = (const float*)d_in[4];
    const float* bl1  = (const float*)d_in[5];
    const float* Wr1  = (const float*)d_in[6];
    const float* Wl2  = (const float*)d_in[7];
    const float* bl2  = (const float*)d_in[8];
    const float* Wr2  = (const float*)d_in[9];
    const float* W1   = (const float*)d_in[10];
    const float* b1   = (const float*)d_in[11];
    const float* W2   = (const float*)d_in[12];
    const float* b2   = (const float*)d_in[13];
    const float* W3   = (const float*)d_in[14];
    const float* b3   = (const float*)d_in[15];

    const int E = in_sizes[1] / 2;
    const int* src = edge;
    const int* dst = edge + E;

    int* rowptr = (int*)d_ws;                                   // N ints
    int* csr    = rowptr + N_NODES;                             // E ints
    int* psum   = csr + (((size_t)E + 3) & ~(size_t)3);         // 128 ints
    ushort* xb   = (ushort*)(psum + 128);                       // N*128
    ushort* aggA = xb + (size_t)N_NODES * F_IN;                 // N*256
    ushort* h    = aggA + (size_t)N_NODES * HID;                // N*256
    ushort* Wt1l = h + (size_t)N_NODES * HID;                   // 256*128
    ushort* Wt1r = Wt1l + 256 * F_IN;
    ushort* Wt2l = Wt1r + 256 * F_IN;                           // 256*256
    ushort* Wt2r = Wt2l + 256 * HID;
    float* out = (float*)d_out;

    const int gemm_grid = (N_NODES + 63) / 64;
    const int gather_grid = (N_NODES + 3) / 4;
    const int nscan = (N_NODES + 1023) / 1024;                  // 98 blocks

    // ---- CSR build ----
    hipMemsetAsync(rowptr, 0, N_NODES * sizeof(int), stream);
    count_kernel<<<(E + 255) / 256, 256, 0, stream>>>(dst, rowptr, E);
    scan1<<<nscan, 256, 0, stream>>>(rowptr, psum, N_NODES);
    scan2<<<1, 128, 0, stream>>>(psum, nscan);
    scan3<<<(N_NODES + 255) / 256, 256, 0, stream>>>(rowptr, psum, N_NODES);
    fill_kernel<<<(E + 255) / 256, 256, 0, stream>>>(src, dst, rowptr, csr, E);

    // ---- conversions ----
    {
        int n4 = N_NODES * F_IN / 4;
        cvt_bf16_kernel<<<(n4 + 255) / 256, 256, 0, stream>>>(x, xb, n4);
        wt_cvt_kernel<<<(256 * F_IN + 255) / 256, 256, 0, stream>>>(Wl1, Wt1l, F_IN);
        wt_cvt_kernel<<<(256 * F_IN + 255) / 256, 256, 0, stream>>>(Wr1, Wt1r, F_IN);
        wt_cvt_kernel<<<(256 * HID + 255) / 256, 256, 0, stream>>>(Wl2, Wt2l, HID);
        wt_cvt_kernel<<<(256 * HID + 255) / 256, 256, 0, stream>>>(Wr2, Wt2r, HID);
    }

    // ---- layer 1 ----
    gather_mean128_b<<<gather_grid, 256, 0, stream>>>(xb, csr, rowptr, aggA, N_NODES);
    gemm_mfma<F_IN, F_IN><<<gemm_grid, 256, 0, stream>>>(aggA, Wt1l, xb, Wt1r, bl1, h, N_NODES);

    // ---- layer 2 ----
    gather_mean256_b<<<gather_grid, 256, 0, stream>>>(h, csr, rowptr, aggA, N_NODES);
    gemm_mfma<HID, HID><<<gemm_grid, 256, 0, stream>>>(aggA, Wt2l, h, Wt2r, bl2, h, N_NODES);

    // ---- MLP head ----
    head_kernel<<<256, 256, 0, stream>>>(h, idxb, xtab, W1, b1, W2, b2, W3, b3, out);
}

// Round 13
// 740.982 us; speedup vs baseline: 11.9448x; 1.1053x over previous
//
#include <hip/hip_runtime.h>
#include <hip/hip_bf16.h>

#define N_NODES 100000
#define HID 256
#define F_IN 128
#define BATCH 16384

using short8 = __attribute__((ext_vector_type(8))) short;
using f32x4  = __attribute__((ext_vector_type(4))) float;

__device__ __forceinline__ ushort f2b(float f) {   // f32 -> bf16 bits, RNE
    union { float f; unsigned u; } v{f};
    unsigned r = (v.u + 0x7fffu + ((v.u >> 16) & 1u)) >> 16;
    return (ushort)r;
}
__device__ __forceinline__ float b2f_lo(unsigned u) { return __uint_as_float(u << 16); }
__device__ __forceinline__ float b2f_hi(unsigned u) { return __uint_as_float(u & 0xffff0000u); }

// ---------------------------------------------------------------- CSR build
__global__ __launch_bounds__(256) void count_kernel(const int* __restrict__ dst,
                                                    int* __restrict__ rowptr, int E) {
    int i = blockIdx.x * blockDim.x + threadIdx.x;
    if (i < E) atomicAdd(&rowptr[dst[i]], 1);
}

// ---- multi-block exclusive scan over data[N] (3 phases) ----
__global__ __launch_bounds__(256) void scan1(int* __restrict__ data,
                                             int* __restrict__ psum, int N) {
    __shared__ int sh[256];
    const int tid = threadIdx.x;
    const int base = blockIdx.x * 1024;
    const int idx0 = base + tid * 4;
    int v0 = 0, v1 = 0, v2 = 0, v3 = 0;
    if (idx0 + 3 < N) {
        int4 q = *(const int4*)(data + idx0);
        v0 = q.x; v1 = q.y; v2 = q.z; v3 = q.w;
    } else {
        if (idx0 + 0 < N) v0 = data[idx0 + 0];
        if (idx0 + 1 < N) v1 = data[idx0 + 1];
        if (idx0 + 2 < N) v2 = data[idx0 + 2];
        if (idx0 + 3 < N) v3 = data[idx0 + 3];
    }
    int tsum = v0 + v1 + v2 + v3;
    sh[tid] = tsum;
    __syncthreads();
    for (int off = 1; off < 256; off <<= 1) {
        int t = (tid >= off) ? sh[tid - off] : 0;
        __syncthreads();
        if (tid >= off) sh[tid] += t;
        __syncthreads();
    }
    if (tid == 255) psum[blockIdx.x] = sh[255];
    int run = sh[tid] - tsum;
    if (idx0 + 3 < N) {
        int4 o;
        o.x = run; run += v0;
        o.y = run; run += v1;
        o.z = run; run += v2;
        o.w = run;
        *(int4*)(data + idx0) = o;
    } else {
        if (idx0 + 0 < N) { data[idx0 + 0] = run; run += v0; }
        if (idx0 + 1 < N) { data[idx0 + 1] = run; run += v1; }
        if (idx0 + 2 < N) { data[idx0 + 2] = run; run += v2; }
    }
}

__global__ __launch_bounds__(128) void scan2(int* __restrict__ psum, int nb) {
    __shared__ int sh[128];
    const int tid = threadIdx.x;
    int v = (tid < nb) ? psum[tid] : 0;
    sh[tid] = v;
    __syncthreads();
    for (int off = 1; off < 128; off <<= 1) {
        int t = (tid >= off) ? sh[tid - off] : 0;
        __syncthreads();
        if (tid >= off) sh[tid] += t;
        __syncthreads();
    }
    if (tid < nb) psum[tid] = sh[tid] - v;
}

__global__ __launch_bounds__(256) void scan3(int* __restrict__ data,
                                             const int* __restrict__ psum, int N) {
    int i = blockIdx.x * blockDim.x + threadIdx.x;
    if (i < N) data[i] += psum[i >> 10];
}

__global__ __launch_bounds__(256) void fill_kernel(const int* __restrict__ src,
                                                   const int* __restrict__ dst,
                                                   int* __restrict__ rowptr,
                                                   int* __restrict__ csr, int E) {
    int i = blockIdx.x * blockDim.x + threadIdx.x;
    if (i < E) {
        int pos = atomicAdd(&rowptr[dst[i]], 1);
        csr[pos] = src[i];
    }
}

// ---------------------------------------------------------------- conversions
__global__ __launch_bounds__(256) void cvt_bf16_kernel(const float* __restrict__ in,
                                                       ushort* __restrict__ out, int n4) {
    int i = blockIdx.x * blockDim.x + threadIdx.x;
    if (i < n4) {
        float4 v = ((const float4*)in)[i];
        ushort4 o;
        o.x = f2b(v.x); o.y = f2b(v.y); o.z = f2b(v.z); o.w = f2b(v.w);
        ((ushort4*)out)[i] = o;
    }
}

// W [K][256] f32  ->  Wt [256][K] bf16 (transpose + convert)
__global__ __launch_bounds__(256) void wt_cvt_kernel(const float* __restrict__ W,
                                                     ushort* __restrict__ Wt, int K) {
    int i = blockIdx.x * blockDim.x + threadIdx.x;
    if (i < 256 * K) {
        int c = i / K, k = i - c * K;
        Wt[i] = f2b(W[k * 256 + c]);
    }
}

// ---------------------------------------------------------------- gather-mean (bf16 in/out)
__global__ __launch_bounds__(256) void gather_mean128_b(const ushort* __restrict__ X,
                                                        const int* __restrict__ csr,
                                                        const int* __restrict__ rowptr,
                                                        ushort* __restrict__ out, int N) {
    const int gt = blockIdx.x * blockDim.x + threadIdx.x;
    const int w = gt >> 6;
    const int lane = gt & 63;
    if (w >= N) return;
    const int start = (w == 0) ? 0 : rowptr[w - 1];
    const int end = rowptr[w];
    float a0 = 0.f, a1 = 0.f, b0 = 0.f, b1 = 0.f;
    int j = start;
    for (; j + 2 <= end; j += 2) {
        int s0 = csr[j], s1 = csr[j + 1];
        unsigned v0 = *(const unsigned*)(X + (size_t)s0 * 128 + lane * 2);
        unsigned v1 = *(const unsigned*)(X + (size_t)s1 * 128 + lane * 2);
        a0 += b2f_lo(v0); a1 += b2f_hi(v0);
        b0 += b2f_lo(v1); b1 += b2f_hi(v1);
    }
    if (j < end) {
        unsigned v0 = *(const unsigned*)(X + (size_t)csr[j] * 128 + lane * 2);
        a0 += b2f_lo(v0); a1 += b2f_hi(v0);
    }
    float inv = 1.0f / fmaxf((float)(end - start), 1.0f);
    unsigned o = (unsigned)f2b((a0 + b0) * inv) | ((unsigned)f2b((a1 + b1) * inv) << 16);
    *(unsigned*)(out + (size_t)w * 128 + lane * 2) = o;
}

__global__ __launch_bounds__(256) void gather_mean256_b(const ushort* __restrict__ X,
                                                        const int* __restrict__ csr,
                                                        const int* __restrict__ rowptr,
                                                        ushort* __restrict__ out, int N) {
    const int gt = blockIdx.x * blockDim.x + threadIdx.x;
    const int w = gt >> 6;
    const int lane = gt & 63;
    if (w >= N) return;
    const int start = (w == 0) ? 0 : rowptr[w - 1];
    const int end = rowptr[w];
    float a0 = 0.f, a1 = 0.f, a2 = 0.f, a3 = 0.f;
    float b0 = 0.f, b1 = 0.f, b2 = 0.f, b3 = 0.f;
    int j = start;
    for (; j + 2 <= end; j += 2) {
        int s0 = csr[j], s1 = csr[j + 1];
        uint2 v0 = *(const uint2*)(X + (size_t)s0 * 256 + lane * 4);
        uint2 v1 = *(const uint2*)(X + (size_t)s1 * 256 + lane * 4);
        a0 += b2f_lo(v0.x); a1 += b2f_hi(v0.x);
        a2 += b2f_lo(v0.y); a3 += b2f_hi(v0.y);
        b0 += b2f_lo(v1.x); b1 += b2f_hi(v1.x);
        b2 += b2f_lo(v1.y); b3 += b2f_hi(v1.y);
    }
    if (j < end) {
        uint2 v0 = *(const uint2*)(X + (size_t)csr[j] * 256 + lane * 4);
        a0 += b2f_lo(v0.x); a1 += b2f_hi(v0.x);
        a2 += b2f_lo(v0.y); a3 += b2f_hi(v0.y);
    }
    float inv = 1.0f / fmaxf((float)(end - start), 1.0f);
    uint2 o;
    o.x = (unsigned)f2b((a0 + b0) * inv) | ((unsigned)f2b((a1 + b1) * inv) << 16);
    o.y = (unsigned)f2b((a2 + b2) * inv) | ((unsigned)f2b((a3 + b3) * inv) << 16);
    *(uint2*)(out + (size_t)w * 256 + lane * 4) = o;
}

// ---------------------------------------------------------------- bf16 MFMA concat-GEMM
template <int K0, int K1>
__global__ __launch_bounds__(256) void gemm_mfma(const ushort* __restrict__ A0,
                                                 const ushort* __restrict__ Wt0,
                                                 const ushort* __restrict__ A1,
                                                 const ushort* __restrict__ Wt1,
                                                 const float* __restrict__ bias,
                                                 ushort* __restrict__ C, int M) {
    __shared__ short As[64][40];    // [row][k], +8 pad
    __shared__ short Bs[256][40];   // [col][k]

    const int tid = threadIdx.x;
    const int wv = tid >> 6;
    const int lane = tid & 63;
    const int m0 = blockIdx.x * 64;
    const int col0 = wv * 64;
    const int arow = tid >> 2;          // 0..63
    const int akc = (tid & 3) * 8;      // 0,8,16,24
    const int l15 = lane & 15;
    const int lk = (lane >> 4) * 8;     // k base within 32

    f32x4 acc[4][4] = {};

    for (int part = 0; part < 2; ++part) {
        const ushort* A = part ? A1 : A0;
        const ushort* Wt = part ? Wt1 : Wt0;
        const int K = part ? K1 : K0;
        for (int k0 = 0; k0 < K; k0 += 32) {
            uint4 av = make_uint4(0u, 0u, 0u, 0u);
            int r = m0 + arow;
            if (r < M) av = *(const uint4*)(A + (size_t)r * K + k0 + akc);
            *(uint4*)&As[arow][akc] = av;
            {
                const ushort* srcp = Wt + (size_t)tid * K + k0;
                uint4 q0 = *(const uint4*)(srcp);
                uint4 q1 = *(const uint4*)(srcp + 8);
                uint4 q2 = *(const uint4*)(srcp + 16);
                uint4 q3 = *(const uint4*)(srcp + 24);
                *(uint4*)&Bs[tid][0] = q0;
                *(uint4*)&Bs[tid][8] = q1;
                *(uint4*)&Bs[tid][16] = q2;
                *(uint4*)&Bs[tid][24] = q3;
            }
            __syncthreads();

            short8 af[4], bg[4];
#pragma unroll
            for (int fi = 0; fi < 4; ++fi)
                af[fi] = *(const short8*)&As[fi * 16 + l15][lk];
#pragma unroll
            for (int fj = 0; fj < 4; ++fj)
                bg[fj] = *(const short8*)&Bs[col0 + fj * 16 + l15][lk];
#pragma unroll
            for (int fi = 0; fi < 4; ++fi)
#pragma unroll
                for (int fj = 0; fj < 4; ++fj)
                    acc[fi][fj] = __builtin_amdgcn_mfma_f32_16x16x32_bf16(
                        af[fi], bg[fj], acc[fi][fj], 0, 0, 0);
            __syncthreads();
        }
    }

    // epilogue: bias + relu -> bf16.  C/D layout: col=lane&15, row=(lane>>4)*4+reg
    const int rbase = (lane >> 4) * 4;
#pragma unroll
    for (int fj = 0; fj < 4; ++fj) {
        int c = col0 + fj * 16 + l15;
        float bv = bias[c];
#pragma unroll
        for (int fi = 0; fi < 4; ++fi) {
#pragma unroll
            for (int rr = 0; rr < 4; ++rr) {
                int r = m0 + fi * 16 + rbase + rr;
                if (r < M) {
                    float o = fmaxf(acc[fi][fj][rr] + bv, 0.f);
                    C[(size_t)r * 256 + c] = f2b(o);
                }
            }
        }
    }
}

// ---------------------------------------------------------------- fused MLP head
// one wave per batch row: grid 4096 x 4 waves; 4-way ILP inner product
__global__ __launch_bounds__(256) void head_kernel(const ushort* __restrict__ h2,
                                                   const int* __restrict__ idxb,
                                                   const float* __restrict__ xtab,
                                                   const float* __restrict__ Wh1,
                                                   const float* __restrict__ bh1,
                                                   const float* __restrict__ Wh2,
                                                   const float* __restrict__ bh2,
                                                   const float* __restrict__ Wh3,
                                                   const float* __restrict__ bh3,
                                                   float* __restrict__ out) {
    __shared__ float zs[4][288];
    const int tid = threadIdx.x;
    const int w = tid >> 6;
    const int lane = tid & 63;
    const int r = blockIdx.x * 4 + w;          // grid*4 == BATCH exactly

    int node = idxb[r];
    uint2 v = *(const uint2*)(h2 + (size_t)node * 256 + lane * 4);
    zs[w][lane * 4 + 0] = b2f_lo(v.x);
    zs[w][lane * 4 + 1] = b2f_hi(v.x);
    zs[w][lane * 4 + 2] = b2f_lo(v.y);
    zs[w][lane * 4 + 3] = b2f_hi(v.y);
    if (lane < 4) {
        float4 t = *(const float4*)(xtab + (size_t)r * 16 + lane * 4);
        zs[w][256 + lane * 4 + 0] = t.x;
        zs[w][256 + lane * 4 + 1] = t.y;
        zs[w][256 + lane * 4 + 2] = t.z;
        zs[w][256 + lane * 4 + 3] = t.w;
    }
    __syncthreads();

    // z1[lane] = relu(bh1[lane] + sum_k zs[k]*Wh1[k][lane]), 4-way ILP
    float s0 = bh1[lane], s1 = 0.f, s2 = 0.f, s3 = 0.f;
#pragma unroll 4
    for (int k = 0; k < 272; k += 4) {
        s0 = fmaf(zs[w][k + 0], Wh1[(k + 0) * 64 + lane], s0);
        s1 = fmaf(zs[w][k + 1], Wh1[(k + 1) * 64 + lane], s1);
        s2 = fmaf(zs[w][k + 2], Wh1[(k + 2) * 64 + lane], s2);
        s3 = fmaf(zs[w][k + 3], Wh1[(k + 3) * 64 + lane], s3);
    }
    float z1 = fmaxf((s0 + s1) + (s2 + s3), 0.f);

    // z2[lane<32] = relu(bh2 + sum_k z1[k]*Wh2[k][lane])
    float acc2 = (lane < 32) ? bh2[lane] : 0.f;
#pragma unroll
    for (int k = 0; k < 64; ++k) {
        float zk = __shfl(z1, k, 64);
        acc2 = fmaf(zk, Wh2[k * 32 + (lane & 31)], acc2);
    }
    float val = (lane < 32) ? fmaxf(acc2, 0.f) * Wh3[lane] : 0.f;
#pragma unroll
    for (int off = 32; off > 0; off >>= 1) val += __shfl_xor(val, off, 64);
    if (lane == 0) out[r] = val + bh3[0];
}

// ---------------------------------------------------------------- launch
// ws: rowptr int[N] | csr int[E] | psum int[128] | xb u16[N*128] | aggA u16[N*256]
//     | h u16[N*256] | Wt1l | Wt1r | Wt2l | Wt2r    (~135 MB)
extern "C" void kernel_launch(void* const* d_in, const int* in_sizes, int n_in,
                              void* d_out, int out_size, void* d_ws, size_t ws_size,
                              hipStream_t stream) {
    const float* x    = (const float*)d_in[0];
    const int*   edge = (const int*)d_in[1];
    const int*   idxb = (const int*)d_in[2];
    const float* xtab = (const float*)d_in[3];
    const float* Wl1  = (const float*)d_in[4];
    const float* bl1  = (const float*)d_in[5];
    const float* Wr1  = (const float*)d_in[6];
    const float* Wl2  = (const float*)d_in[7];
    const float* bl2  = (const float*)d_in[8];
    const float* Wr2  = (const float*)d_in[9];
    const float* W1   = (const float*)d_in[10];
    const float* b1   = (const float*)d_in[11];
    const float* W2   = (const float*)d_in[12];
    const float* b2   = (const float*)d_in[13];
    const float* W3   = (const float*)d_in[14];
    const float* b3   = (const float*)d_in[15];

    const int E = in_sizes[1] / 2;
    const int* src = edge;
    const int* dst = edge + E;

    int* rowptr = (int*)d_ws;                                   // N ints
    int* csr    = rowptr + N_NODES;                             // E ints
    int* psum   = csr + (((size_t)E + 3) & ~(size_t)3);         // 128 ints
    ushort* xb   = (ushort*)(psum + 128);                       // N*128
    ushort* aggA = xb + (size_t)N_NODES * F_IN;                 // N*256
    ushort* h    = aggA + (size_t)N_NODES * HID;                // N*256
    ushort* Wt1l = h + (size_t)N_NODES * HID;                   // 256*128
    ushort* Wt1r = Wt1l + 256 * F_IN;
    ushort* Wt2l = Wt1r + 256 * F_IN;                           // 256*256
    ushort* Wt2r = Wt2l + 256 * HID;
    float* out = (float*)d_out;

    const int gemm_grid = (N_NODES + 63) / 64;
    const int gather_grid = (N_NODES + 3) / 4;
    const int nscan = (N_NODES + 1023) / 1024;                  // 98 blocks

    // ---- CSR build ----
    hipMemsetAsync(rowptr, 0, N_NODES * sizeof(int), stream);
    count_kernel<<<(E + 255) / 256, 256, 0, stream>>>(dst, rowptr, E);
    scan1<<<nscan, 256, 0, stream>>>(rowptr, psum, N_NODES);
    scan2<<<1, 128, 0, stream>>>(psum, nscan);
    scan3<<<(N_NODES + 255) / 256, 256, 0, stream>>>(rowptr, psum, N_NODES);
    fill_kernel<<<(E + 255) / 256, 256, 0, stream>>>(src, dst, rowptr, csr, E);

    // ---- conversions ----
    {
        int n4 = N_NODES * F_IN / 4;
        cvt_bf16_kernel<<<(n4 + 255) / 256, 256, 0, stream>>>(x, xb, n4);
        wt_cvt_kernel<<<(256 * F_IN + 255) / 256, 256, 0, stream>>>(Wl1, Wt1l, F_IN);
        wt_cvt_kernel<<<(256 * F_IN + 255) / 256, 256, 0, stream>>>(Wr1, Wt1r, F_IN);
        wt_cvt_kernel<<<(256 * HID + 255) / 256, 256, 0, stream>>>(Wl2, Wt2l, HID);
        wt_cvt_kernel<<<(256 * HID + 255) / 256, 256, 0, stream>>>(Wr2, Wt2r, HID);
    }

    // ---- layer 1 ----
    gather_mean128_b<<<gather_grid, 256, 0, stream>>>(xb, csr, rowptr, aggA, N_NODES);
    gemm_mfma<F_IN, F_IN><<<gemm_grid, 256, 0, stream>>>(aggA, Wt1l, xb, Wt1r, bl1, h, N_NODES);

    // ---- layer 2 ----
    gather_mean256_b<<<gather_grid, 256, 0, stream>>>(h, csr, rowptr, aggA, N_NODES);
    gemm_mfma<HID, HID><<<gemm_grid, 256, 0, stream>>>(aggA, Wt2l, h, Wt2r, bl2, h, N_NODES);

    // ---- MLP head ----
    head_kernel<<<BATCH / 4, 256, 0, stream>>>(h, idxb, xtab, W1, b1, W2, b2, W3, b3, out);
}

// Round 15
// 722.445 us; speedup vs baseline: 12.2513x; 1.0257x over previous
//
#include <hip/hip_runtime.h>
#include <hip/hip_bf16.h>

#define N_NODES 100000
#define HID 256
#define F_IN 128
#define BATCH 16384

using short8 = __attribute__((ext_vector_type(8))) short;
using f32x4  = __attribute__((ext_vector_type(4))) float;

__device__ __forceinline__ ushort f2b(float f) {   // f32 -> bf16 bits, RNE
    union { float f; unsigned u; } v{f};
    unsigned r = (v.u + 0x7fffu + ((v.u >> 16) & 1u)) >> 16;
    return (ushort)r;
}
__device__ __forceinline__ float b2f_lo(unsigned u) { return __uint_as_float(u << 16); }
__device__ __forceinline__ float b2f_hi(unsigned u) { return __uint_as_float(u & 0xffff0000u); }

// ---------------------------------------------------------------- CSR build
__global__ __launch_bounds__(256) void count_kernel(const int* __restrict__ dst,
                                                    int* __restrict__ rowptr, int E) {
    int i = blockIdx.x * blockDim.x + threadIdx.x;
    if (i < E) atomicAdd(&rowptr[dst[i]], 1);
}

// ---- multi-block exclusive scan over data[N] (3 phases) ----
__global__ __launch_bounds__(256) void scan1(int* __restrict__ data,
                                             int* __restrict__ psum, int N) {
    __shared__ int sh[256];
    const int tid = threadIdx.x;
    const int base = blockIdx.x * 1024;
    const int idx0 = base + tid * 4;
    int v0 = 0, v1 = 0, v2 = 0, v3 = 0;
    if (idx0 + 3 < N) {
        int4 q = *(const int4*)(data + idx0);
        v0 = q.x; v1 = q.y; v2 = q.z; v3 = q.w;
    } else {
        if (idx0 + 0 < N) v0 = data[idx0 + 0];
        if (idx0 + 1 < N) v1 = data[idx0 + 1];
        if (idx0 + 2 < N) v2 = data[idx0 + 2];
        if (idx0 + 3 < N) v3 = data[idx0 + 3];
    }
    int tsum = v0 + v1 + v2 + v3;
    sh[tid] = tsum;
    __syncthreads();
    for (int off = 1; off < 256; off <<= 1) {
        int t = (tid >= off) ? sh[tid - off] : 0;
        __syncthreads();
        if (tid >= off) sh[tid] += t;
        __syncthreads();
    }
    if (tid == 255) psum[blockIdx.x] = sh[255];
    int run = sh[tid] - tsum;
    if (idx0 + 3 < N) {
        int4 o;
        o.x = run; run += v0;
        o.y = run; run += v1;
        o.z = run; run += v2;
        o.w = run;
        *(int4*)(data + idx0) = o;
    } else {
        if (idx0 + 0 < N) { data[idx0 + 0] = run; run += v0; }
        if (idx0 + 1 < N) { data[idx0 + 1] = run; run += v1; }
        if (idx0 + 2 < N) { data[idx0 + 2] = run; run += v2; }
    }
}

__global__ __launch_bounds__(128) void scan2(int* __restrict__ psum, int nb) {
    __shared__ int sh[128];
    const int tid = threadIdx.x;
    int v = (tid < nb) ? psum[tid] : 0;
    sh[tid] = v;
    __syncthreads();
    for (int off = 1; off < 128; off <<= 1) {
        int t = (tid >= off) ? sh[tid - off] : 0;
        __syncthreads();
        if (tid >= off) sh[tid] += t;
        __syncthreads();
    }
    if (tid < nb) psum[tid] = sh[tid] - v;
}

__global__ __launch_bounds__(256) void scan3(int* __restrict__ data,
                                             const int* __restrict__ psum, int N) {
    int i = blockIdx.x * blockDim.x + threadIdx.x;
    if (i < N) data[i] += psum[i >> 10];
}

// fill pass p: append only edges whose dst>>15 == p (csr write window ~2MB, L2-resident).
// NT loads keep the streamed edge list from evicting dirty csr lines.
__global__ __launch_bounds__(256) void fill_range_kernel(const int* __restrict__ src,
                                                         const int* __restrict__ dst,
                                                         int* __restrict__ rowptr,
                                                         int* __restrict__ csr,
                                                         int E, int pass) {
    int i = blockIdx.x * blockDim.x + threadIdx.x;
    if (i < E) {
        int d = __builtin_nontemporal_load(&dst[i]);
        if ((d >> 15) == pass) {
            int s = __builtin_nontemporal_load(&src[i]);
            int pos = atomicAdd(&rowptr[d], 1);
            csr[pos] = s;
        }
    }
}

// ---------------------------------------------------------------- conversions
__global__ __launch_bounds__(256) void cvt_bf16_kernel(const float* __restrict__ in,
                                                       ushort* __restrict__ out, int n4) {
    int i = blockIdx.x * blockDim.x + threadIdx.x;
    if (i < n4) {
        float4 v = ((const float4*)in)[i];
        ushort4 o;
        o.x = f2b(v.x); o.y = f2b(v.y); o.z = f2b(v.z); o.w = f2b(v.w);
        ((ushort4*)out)[i] = o;
    }
}

// W [K][256] f32  ->  Wt [256][K] bf16 (transpose + convert)
__global__ __launch_bounds__(256) void wt_cvt_kernel(const float* __restrict__ W,
                                                     ushort* __restrict__ Wt, int K) {
    int i = blockIdx.x * blockDim.x + threadIdx.x;
    if (i < 256 * K) {
        int c = i / K, k = i - c * K;
        Wt[i] = f2b(W[k * 256 + c]);
    }
}

// ---------------------------------------------------------------- gather-mean (bf16 in/out)
__global__ __launch_bounds__(256) void gather_mean128_b(const ushort* __restrict__ X,
                                                        const int* __restrict__ csr,
                                                        const int* __restrict__ rowptr,
                                                        ushort* __restrict__ out, int N) {
    const int gt = blockIdx.x * blockDim.x + threadIdx.x;
    const int w = gt >> 6;
    const int lane = gt & 63;
    if (w >= N) return;
    const int start = (w == 0) ? 0 : rowptr[w - 1];
    const int end = rowptr[w];
    float a0 = 0.f, a1 = 0.f, b0 = 0.f, b1 = 0.f;
    int j = start;
    for (; j + 2 <= end; j += 2) {
        int s0 = csr[j], s1 = csr[j + 1];
        unsigned v0 = *(const unsigned*)(X + (size_t)s0 * 128 + lane * 2);
        unsigned v1 = *(const unsigned*)(X + (size_t)s1 * 128 + lane * 2);
        a0 += b2f_lo(v0); a1 += b2f_hi(v0);
        b0 += b2f_lo(v1); b1 += b2f_hi(v1);
    }
    if (j < end) {
        unsigned v0 = *(const unsigned*)(X + (size_t)csr[j] * 128 + lane * 2);
        a0 += b2f_lo(v0); a1 += b2f_hi(v0);
    }
    float inv = 1.0f / fmaxf((float)(end - start), 1.0f);
    unsigned o = (unsigned)f2b((a0 + b0) * inv) | ((unsigned)f2b((a1 + b1) * inv) << 16);
    *(unsigned*)(out + (size_t)w * 128 + lane * 2) = o;
}

__global__ __launch_bounds__(256) void gather_mean256_b(const ushort* __restrict__ X,
                                                        const int* __restrict__ csr,
                                                        const int* __restrict__ rowptr,
                                                        ushort* __restrict__ out, int N) {
    const int gt = blockIdx.x * blockDim.x + threadIdx.x;
    const int w = gt >> 6;
    const int lane = gt & 63;
    if (w >= N) return;
    const int start = (w == 0) ? 0 : rowptr[w - 1];
    const int end = rowptr[w];
    float a0 = 0.f, a1 = 0.f, a2 = 0.f, a3 = 0.f;
    float b0 = 0.f, b1 = 0.f, b2 = 0.f, b3 = 0.f;
    int j = start;
    for (; j + 2 <= end; j += 2) {
        int s0 = csr[j], s1 = csr[j + 1];
        uint2 v0 = *(const uint2*)(X + (size_t)s0 * 256 + lane * 4);
        uint2 v1 = *(const uint2*)(X + (size_t)s1 * 256 + lane * 4);
        a0 += b2f_lo(v0.x); a1 += b2f_hi(v0.x);
        a2 += b2f_lo(v0.y); a3 += b2f_hi(v0.y);
        b0 += b2f_lo(v1.x); b1 += b2f_hi(v1.x);
        b2 += b2f_lo(v1.y); b3 += b2f_hi(v1.y);
    }
    if (j < end) {
        uint2 v0 = *(const uint2*)(X + (size_t)csr[j] * 256 + lane * 4);
        a0 += b2f_lo(v0.x); a1 += b2f_hi(v0.x);
        a2 += b2f_lo(v0.y); a3 += b2f_hi(v0.y);
    }
    float inv = 1.0f / fmaxf((float)(end - start), 1.0f);
    uint2 o;
    o.x = (unsigned)f2b((a0 + b0) * inv) | ((unsigned)f2b((a1 + b1) * inv) << 16);
    o.y = (unsigned)f2b((a2 + b2) * inv) | ((unsigned)f2b((a3 + b3) * inv) << 16);
    *(uint2*)(out + (size_t)w * 256 + lane * 4) = o;
}

// ---------------------------------------------------------------- bf16 MFMA concat-GEMM
template <int K0, int K1>
__global__ __launch_bounds__(256) void gemm_mfma(const ushort* __restrict__ A0,
                                                 const ushort* __restrict__ Wt0,
                                                 const ushort* __restrict__ A1,
                                                 const ushort* __restrict__ Wt1,
                                                 const float* __restrict__ bias,
                                                 ushort* __restrict__ C, int M) {
    __shared__ short As[64][40];    // [row][k], +8 pad
    __shared__ short Bs[256][40];   // [col][k]

    const int tid = threadIdx.x;
    const int wv = tid >> 6;
    const int lane = tid & 63;
    const int m0 = blockIdx.x * 64;
    const int col0 = wv * 64;
    const int arow = tid >> 2;          // 0..63
    const int akc = (tid & 3) * 8;      // 0,8,16,24
    const int l15 = lane & 15;
    const int lk = (lane >> 4) * 8;     // k base within 32

    f32x4 acc[4][4] = {};

    for (int part = 0; part < 2; ++part) {
        const ushort* A = part ? A1 : A0;
        const ushort* Wt = part ? Wt1 : Wt0;
        const int K = part ? K1 : K0;
        for (int k0 = 0; k0 < K; k0 += 32) {
            uint4 av = make_uint4(0u, 0u, 0u, 0u);
            int r = m0 + arow;
            if (r < M) av = *(const uint4*)(A + (size_t)r * K + k0 + akc);
            *(uint4*)&As[arow][akc] = av;
            {
                const ushort* srcp = Wt + (size_t)tid * K + k0;
                uint4 q0 = *(const uint4*)(srcp);
                uint4 q1 = *(const uint4*)(srcp + 8);
                uint4 q2 = *(const uint4*)(srcp + 16);
                uint4 q3 = *(const uint4*)(srcp + 24);
                *(uint4*)&Bs[tid][0] = q0;
                *(uint4*)&Bs[tid][8] = q1;
                *(uint4*)&Bs[tid][16] = q2;
                *(uint4*)&Bs[tid][24] = q3;
            }
            __syncthreads();

            short8 af[4], bg[4];
#pragma unroll
            for (int fi = 0; fi < 4; ++fi)
                af[fi] = *(const short8*)&As[fi * 16 + l15][lk];
#pragma unroll
            for (int fj = 0; fj < 4; ++fj)
                bg[fj] = *(const short8*)&Bs[col0 + fj * 16 + l15][lk];
#pragma unroll
            for (int fi = 0; fi < 4; ++fi)
#pragma unroll
                for (int fj = 0; fj < 4; ++fj)
                    acc[fi][fj] = __builtin_amdgcn_mfma_f32_16x16x32_bf16(
                        af[fi], bg[fj], acc[fi][fj], 0, 0, 0);
            __syncthreads();
        }
    }

    // epilogue: bias + relu -> bf16.  C/D layout: col=lane&15, row=(lane>>4)*4+reg
    const int rbase = (lane >> 4) * 4;
#pragma unroll
    for (int fj = 0; fj < 4; ++fj) {
        int c = col0 + fj * 16 + l15;
        float bv = bias[c];
#pragma unroll
        for (int fi = 0; fi < 4; ++fi) {
#pragma unroll
            for (int rr = 0; rr < 4; ++rr) {
                int r = m0 + fi * 16 + rbase + rr;
                if (r < M) {
                    float o = fmaxf(acc[fi][fj][rr] + bv, 0.f);
                    C[(size_t)r * 256 + c] = f2b(o);
                }
            }
        }
    }
}

// ---------------------------------------------------------------- fused MLP head
// one wave per batch row; 4-way ILP inner product
__global__ __launch_bounds__(256) void head_kernel(const ushort* __restrict__ h2,
                                                   const int* __restrict__ idxb,
                                                   const float* __restrict__ xtab,
                                                   const float* __restrict__ Wh1,
                                                   const float* __restrict__ bh1,
                                                   const float* __restrict__ Wh2,
                                                   const float* __restrict__ bh2,
                                                   const float* __restrict__ Wh3,
                                                   const float* __restrict__ bh3,
                                                   float* __restrict__ out) {
    __shared__ float zs[4][288];
    const int tid = threadIdx.x;
    const int w = tid >> 6;
    const int lane = tid & 63;
    const int r = blockIdx.x * 4 + w;          // grid*4 == BATCH exactly

    int node = idxb[r];
    uint2 v = *(const uint2*)(h2 + (size_t)node * 256 + lane * 4);
    zs[w][lane * 4 + 0] = b2f_lo(v.x);
    zs[w][lane * 4 + 1] = b2f_hi(v.x);
    zs[w][lane * 4 + 2] = b2f_lo(v.y);
    zs[w][lane * 4 + 3] = b2f_hi(v.y);
    if (lane < 4) {
        float4 t = *(const float4*)(xtab + (size_t)r * 16 + lane * 4);
        zs[w][256 + lane * 4 + 0] = t.x;
        zs[w][256 + lane * 4 + 1] = t.y;
        zs[w][256 + lane * 4 + 2] = t.z;
        zs[w][256 + lane * 4 + 3] = t.w;
    }
    __syncthreads();

    float s0 = bh1[lane], s1 = 0.f, s2 = 0.f, s3 = 0.f;
#pragma unroll 4
    for (int k = 0; k < 272; k += 4) {
        s0 = fmaf(zs[w][k + 0], Wh1[(k + 0) * 64 + lane], s0);
        s1 = fmaf(zs[w][k + 1], Wh1[(k + 1) * 64 + lane], s1);
        s2 = fmaf(zs[w][k + 2], Wh1[(k + 2) * 64 + lane], s2);
        s3 = fmaf(zs[w][k + 3], Wh1[(k + 3) * 64 + lane], s3);
    }
    float z1 = fmaxf((s0 + s1) + (s2 + s3), 0.f);

    float acc2 = (lane < 32) ? bh2[lane] : 0.f;
#pragma unroll
    for (int k = 0; k < 64; ++k) {
        float zk = __shfl(z1, k, 64);
        acc2 = fmaf(zk, Wh2[k * 32 + (lane & 31)], acc2);
    }
    float val = (lane < 32) ? fmaxf(acc2, 0.f) * Wh3[lane] : 0.f;
#pragma unroll
    for (int off = 32; off > 0; off >>= 1) val += __shfl_xor(val, off, 64);
    if (lane == 0) out[r] = val + bh3[0];
}

// ---------------------------------------------------------------- launch
// ws: rowptr int[N] | csr int[E] | psum int[128] | xb u16[N*128] | aggA u16[N*256]
//     | h u16[N*256] | Wt1l | Wt1r | Wt2l | Wt2r    (~135 MB)
extern "C" void kernel_launch(void* const* d_in, const int* in_sizes, int n_in,
                              void* d_out, int out_size, void* d_ws, size_t ws_size,
                              hipStream_t stream) {
    const float* x    = (const float*)d_in[0];
    const int*   edge = (const int*)d_in[1];
    const int*   idxb = (const int*)d_in[2];
    const float* xtab = (const float*)d_in[3];
    const float* Wl1  = (const float*)d_in[4];
    const float* bl1  = (const float*)d_in[5];
    const float* Wr1  = (const float*)d_in[6];
    const float* Wl2  = (const float*)d_in[7];
    const float* bl2  = (const float*)d_in[8];
    const float* Wr2  = (const float*)d_in[9];
    const float* W1   = (const float*)d_in[10];
    const float* b1   = (const float*)d_in[11];
    const float* W2   = (const float*)d_in[12];
    const float* b2   = (const float*)d_in[13];
    const float* W3   = (const float*)d_in[14];
    const float* b3   = (const float*)d_in[15];

    const int E = in_sizes[1] / 2;
    const int* src = edge;
    const int* dst = edge + E;

    int* rowptr = (int*)d_ws;                                   // N ints
    int* csr    = rowptr + N_NODES;                             // E ints
    int* psum   = csr + (((size_t)E + 3) & ~(size_t)3);         // 128 ints
    ushort* xb   = (ushort*)(psum + 128);                       // N*128
    ushort* aggA = xb + (size_t)N_NODES * F_IN;                 // N*256
    ushort* h    = aggA + (size_t)N_NODES * HID;                // N*256
    ushort* Wt1l = h + (size_t)N_NODES * HID;                   // 256*128
    ushort* Wt1r = Wt1l + 256 * F_IN;
    ushort* Wt2l = Wt1r + 256 * F_IN;                           // 256*256
    ushort* Wt2r = Wt2l + 256 * HID;
    float* out = (float*)d_out;

    const int gemm_grid = (N_NODES + 63) / 64;
    const int gather_grid = (N_NODES + 3) / 4;
    const int nscan = (N_NODES + 1023) / 1024;                  // 98 blocks

    // ---- CSR build ----
    hipMemsetAsync(rowptr, 0, N_NODES * sizeof(int), stream);
    count_kernel<<<(E + 255) / 256, 256, 0, stream>>>(dst, rowptr, E);
    scan1<<<nscan, 256, 0, stream>>>(rowptr, psum, N_NODES);
    scan2<<<1, 128, 0, stream>>>(psum, nscan);
    scan3<<<(N_NODES + 255) / 256, 256, 0, stream>>>(rowptr, psum, N_NODES);
    for (int pass = 0; pass < 4; ++pass)    // dst>>15 == pass covers N=100000
        fill_range_kernel<<<(E + 255) / 256, 256, 0, stream>>>(src, dst, rowptr, csr, E, pass);

    // ---- conversions ----
    {
        int n4 = N_NODES * F_IN / 4;
        cvt_bf16_kernel<<<(n4 + 255) / 256, 256, 0, stream>>>(x, xb, n4);
        wt_cvt_kernel<<<(256 * F_IN + 255) / 256, 256, 0, stream>>>(Wl1, Wt1l, F_IN);
        wt_cvt_kernel<<<(256 * F_IN + 255) / 256, 256, 0, stream>>>(Wr1, Wt1r, F_IN);
        wt_cvt_kernel<<<(256 * HID + 255) / 256, 256, 0, stream>>>(Wl2, Wt2l, HID);
        wt_cvt_kernel<<<(256 * HID + 255) / 256, 256, 0, stream>>>(Wr2, Wt2r, HID);
    }

    // ---- layer 1 ----
    gather_mean128_b<<<gather_grid, 256, 0, stream>>>(xb, csr, rowptr, aggA, N_NODES);
    gemm_mfma<F_IN, F_IN><<<gemm_grid, 256, 0, stream>>>(aggA, Wt1l, xb, Wt1r, bl1, h, N_NODES);

    // ---- layer 2 ----
    gather_mean256_b<<<gather_grid, 256, 0, stream>>>(h, csr, rowptr, aggA, N_NODES);
    gemm_mfma<HID, HID><<<gemm_grid, 256, 0, stream>>>(aggA, Wt2l, h, Wt2r, bl2, h, N_NODES);

    // ---- MLP head ----
    head_kernel<<<BATCH / 4, 256, 0, stream>>>(h, idxb, xtab, W1, b1, W2, b2, W3, b3, out);
}